// Round 5
// baseline (1064.132 us; speedup 1.0000x reference)
//
#include <hip/hip_runtime.h>
#include <math.h>

// ---------------- CSR build ----------------
__global__ __launch_bounds__(256) void hist_k(const int* __restrict__ dst, int* __restrict__ deg, int e) {
    int i = blockIdx.x * 256 + threadIdx.x;
    if (i < e) atomicAdd(&deg[dst[i]], 1);
}

__global__ __launch_bounds__(256) void scan1_k(const int* __restrict__ deg, int* __restrict__ rowptr,
                                               int* __restrict__ bsum, int n) {
    __shared__ int sh[256];
    int tid = threadIdx.x;
    int sid = blockIdx.x * 256 + tid;
    int v = (sid < n) ? deg[sid] : 0;
    sh[tid] = v; __syncthreads();
    for (int off = 1; off < 256; off <<= 1) {
        int t = (tid >= off) ? sh[tid - off] : 0;
        __syncthreads();
        sh[tid] += t;
        __syncthreads();
    }
    if (sid < n) rowptr[sid + 1] = sh[tid];
    if (tid == 255) bsum[blockIdx.x] = sh[255];
}

__global__ __launch_bounds__(512) void scan2_k(int* __restrict__ bsum, int nb) {
    __shared__ int sh[512];
    int tid = threadIdx.x;
    sh[tid] = (tid < nb) ? bsum[tid] : 0;
    __syncthreads();
    for (int off = 1; off < 512; off <<= 1) {
        int t = (tid >= off) ? sh[tid - off] : 0;
        __syncthreads();
        sh[tid] += t;
        __syncthreads();
    }
    if (tid < nb) bsum[tid] = sh[tid];
}

__global__ __launch_bounds__(256) void scan3_k(int* __restrict__ rowptr, const int* __restrict__ bsum, int n) {
    int sid = blockIdx.x * 256 + threadIdx.x;
    if (sid == 0) rowptr[0] = 0;
    if (sid < n && blockIdx.x > 0) rowptr[sid + 1] += bsum[blockIdx.x - 1];
}

__global__ __launch_bounds__(256) void fill_k(const int* __restrict__ src, const int* __restrict__ dst,
                                              const int* __restrict__ rowptr, int* __restrict__ cursor,
                                              int* __restrict__ csrc, int* __restrict__ cdst, int e) {
    int i = blockIdx.x * 256 + threadIdx.x;
    if (i < e) {
        int d = dst[i];
        int pos = rowptr[d] + atomicAdd(&cursor[d], 1);
        csrc[pos] = src[i];
        cdst[pos] = d;
    }
}

// ---------------- fp32 GEMM: C[M,128] = A[M,128] @ W[128,128], fused el/er ----------------
// BM=64, 128 threads (2 waves), 8x8 micro-tile, register-prefetch double buffering.
__global__ __launch_bounds__(128, 3) void gemm_feat_k(const float* __restrict__ A, const float* __restrict__ W,
                                                      const float* __restrict__ al, const float* __restrict__ ar,
                                                      float* __restrict__ C, float* __restrict__ el,
                                                      float* __restrict__ er, int M) {
    __shared__ float As[32][68];    // [k][m] transposed, padded (68*4B=272B row, 16B-aligned)
    __shared__ float Bs[32][128];   // [k][n]
    int tid = threadIdx.x;
    int m0 = blockIdx.x * 64;
    int tr = tid >> 4;        // 0..7
    int tc = tid & 15;        // 0..15
    float4 alA = *(const float4*)(al + tc * 4);
    float4 alB = *(const float4*)(al + 64 + tc * 4);
    float4 arA = *(const float4*)(ar + tc * 4);
    float4 arB = *(const float4*)(ar + 64 + tc * 4);
    float acc[8][8];
    #pragma unroll
    for (int i = 0; i < 8; i++)
        #pragma unroll
        for (int j = 0; j < 8; j++) acc[i][j] = 0.f;

    int arow = tid >> 1, acg = tid & 1;   // A: 64 rows x 2 chunk-groups
    int bkr = tid >> 5, bcg = tid & 31;   // B: 4 k-rows x 32 col-chunks

    int mm = min(m0 + arow, M - 1);
    const float* Arow = A + (size_t)mm * 128;

    float4 pa[4], pb[8];
    // prefetch k-block 0
    #pragma unroll
    for (int j = 0; j < 4; j++) pa[j] = *(const float4*)(Arow + (acg * 4 + j) * 4);
    #pragma unroll
    for (int rp = 0; rp < 8; rp++) pb[rp] = *(const float4*)(W + (size_t)(rp * 4 + bkr) * 128 + bcg * 4);

    for (int kb = 0; kb < 128; kb += 32) {
        // write prefetched regs to LDS
        #pragma unroll
        for (int j = 0; j < 4; j++) {
            int kr = acg * 16 + j * 4;
            As[kr + 0][arow] = pa[j].x;
            As[kr + 1][arow] = pa[j].y;
            As[kr + 2][arow] = pa[j].z;
            As[kr + 3][arow] = pa[j].w;
        }
        #pragma unroll
        for (int rp = 0; rp < 8; rp++)
            *(float4*)&Bs[rp * 4 + bkr][bcg * 4] = pb[rp];
        __syncthreads();
        // issue next k-block's global loads; consumed at next iteration's LDS write,
        // so HBM latency hides under the 32-step compute below
        if (kb < 96) {
            int kn = kb + 32;
            #pragma unroll
            for (int j = 0; j < 4; j++) pa[j] = *(const float4*)(Arow + kn + (acg * 4 + j) * 4);
            #pragma unroll
            for (int rp = 0; rp < 8; rp++) pb[rp] = *(const float4*)(W + (size_t)(kn + rp * 4 + bkr) * 128 + bcg * 4);
        }
        #pragma unroll
        for (int k = 0; k < 32; ++k) {
            float a[8], b[8];
            *(float4*)(a)     = *(float4*)&As[k][tr * 4];
            *(float4*)(a + 4) = *(float4*)&As[k][32 + tr * 4];
            *(float4*)(b)     = *(float4*)&Bs[k][tc * 4];
            *(float4*)(b + 4) = *(float4*)&Bs[k][64 + tc * 4];
            #pragma unroll
            for (int i = 0; i < 8; i++)
                #pragma unroll
                for (int j = 0; j < 8; j++) acc[i][j] += a[i] * b[j];
        }
        __syncthreads();
    }
    // store C
    #pragma unroll
    for (int i = 0; i < 8; i++) {
        int m = m0 + ((i < 4) ? (tr * 4 + i) : (32 + tr * 4 + (i - 4)));
        if (m < M) {
            *(float4*)(C + (size_t)m * 128 + tc * 4)      = make_float4(acc[i][0], acc[i][1], acc[i][2], acc[i][3]);
            *(float4*)(C + (size_t)m * 128 + 64 + tc * 4) = make_float4(acc[i][4], acc[i][5], acc[i][6], acc[i][7]);
        }
    }
    // fused el/er: reduce per-head dot partials across the 8 lanes sharing a column half
    #pragma unroll
    for (int i = 0; i < 8; i++) {
        float plA = acc[i][0] * alA.x + acc[i][1] * alA.y + acc[i][2] * alA.z + acc[i][3] * alA.w;
        float plB = acc[i][4] * alB.x + acc[i][5] * alB.y + acc[i][6] * alB.z + acc[i][7] * alB.w;
        float prA = acc[i][0] * arA.x + acc[i][1] * arA.y + acc[i][2] * arA.z + acc[i][3] * arA.w;
        float prB = acc[i][4] * arB.x + acc[i][5] * arB.y + acc[i][6] * arB.z + acc[i][7] * arB.w;
        #pragma unroll
        for (int off = 1; off < 8; off <<= 1) {
            plA += __shfl_xor(plA, off);
            plB += __shfl_xor(plB, off);
            prA += __shfl_xor(prA, off);
            prB += __shfl_xor(prB, off);
        }
        if ((tc & 7) == 0) {
            int m = m0 + ((i < 4) ? (tr * 4 + i) : (32 + tr * 4 + (i - 4)));
            if (m < M) {
                int hA = tc >> 3;
                el[m * 4 + hA]     = plA;
                el[m * 4 + hA + 2] = plB;
                er[m * 4 + hA]     = prA;
                er[m * 4 + hA + 2] = prB;
            }
        }
    }
}

// ---------------- per-edge attention weights (CSR order, coalesced) ----------------
__global__ __launch_bounds__(256) void edgew_k(const int* __restrict__ csrc, const int* __restrict__ cdst,
                                               const float* __restrict__ el, const float* __restrict__ er,
                                               float* __restrict__ wbuf, int e) {
    int p = blockIdx.x * 256 + threadIdx.x;
    if (p >= e) return;
    int s = csrc[p], d = cdst[p];
    float4 l4 = *(const float4*)(el + (size_t)s * 4);
    float4 r4 = *(const float4*)(er + (size_t)d * 4);
    float e0 = l4.x + r4.x, e1 = l4.y + r4.y, e2 = l4.z + r4.z, e3 = l4.w + r4.w;
    e0 = (e0 > 0.f) ? e0 : 0.2f * e0;
    e1 = (e1 > 0.f) ? e1 : 0.2f * e1;
    e2 = (e2 > 0.f) ? e2 : 0.2f * e2;
    e3 = (e3 > 0.f) ? e3 : 0.2f * e3;
    *(float4*)(wbuf + (size_t)p * 4) = make_float4(__expf(e0), __expf(e1), __expf(e2), __expf(e3));
}

// ---------------- per-node aggregate + bias + ELU ----------------
__global__ __launch_bounds__(256) void aggregate_k(const float* __restrict__ feat, const float* __restrict__ wbuf,
                                                   const int* __restrict__ rowptr, const int* __restrict__ csrc,
                                                   const float* __restrict__ bias, float* __restrict__ out, int n) {
    int wid = threadIdx.x >> 6;
    int lane = threadIdx.x & 63;
    int node = blockIdx.x * 4 + wid;
    if (node >= n) return;
    int h = lane >> 4;
    int p0 = rowptr[node], p1 = rowptr[node + 1];
    float2 b2 = *(const float2*)(bias + lane * 2);
    float lsum = 0.f, a0 = 0.f, a1 = 0.f;
    int p = p0;
    for (; p + 4 <= p1; p += 4) {
        int s0 = csrc[p], s1 = csrc[p + 1], s2 = csrc[p + 2], s3 = csrc[p + 3];
        float w0 = wbuf[(size_t)p * 4 + h];
        float w1 = wbuf[(size_t)(p + 1) * 4 + h];
        float w2 = wbuf[(size_t)(p + 2) * 4 + h];
        float w3 = wbuf[(size_t)(p + 3) * 4 + h];
        float2 f0 = *(const float2*)(feat + (size_t)s0 * 128 + lane * 2);
        float2 f1 = *(const float2*)(feat + (size_t)s1 * 128 + lane * 2);
        float2 f2 = *(const float2*)(feat + (size_t)s2 * 128 + lane * 2);
        float2 f3 = *(const float2*)(feat + (size_t)s3 * 128 + lane * 2);
        lsum += (w0 + w1) + (w2 + w3);
        a0 += w0 * f0.x + w1 * f1.x + w2 * f2.x + w3 * f3.x;
        a1 += w0 * f0.y + w1 * f1.y + w2 * f2.y + w3 * f3.y;
    }
    for (; p < p1; ++p) {
        int s = csrc[p];
        float w = wbuf[(size_t)p * 4 + h];
        float2 f = *(const float2*)(feat + (size_t)s * 128 + lane * 2);
        lsum += w;
        a0 += w * f.x;
        a1 += w * f.y;
    }
    float inv = 1.f / fmaxf(lsum, 1e-9f);
    float v0 = a0 * inv + b2.x;
    float v1 = a1 * inv + b2.y;
    v0 = (v0 > 0.f) ? v0 : expm1f(v0);
    v1 = (v1 > 0.f) ? v1 : expm1f(v1);
    *(float2*)(out + (size_t)node * 128 + lane * 2) = make_float2(v0, v1);
}

// ---------------- projection: hp[N,32] = h[N,128] @ Wp[128,32] + bp ----------------
__global__ __launch_bounds__(256) void proj_k(const float* __restrict__ h, const float* __restrict__ Wp,
                                              const float* __restrict__ bp, float* __restrict__ hp, int n) {
    __shared__ float Ws[128 * 32];
    __shared__ float Hs[32][132];
    int tid = threadIdx.x;
    for (int i = tid; i < 4096; i += 256) Ws[i] = Wp[i];
    int n0 = blockIdx.x * 32;
    for (int i = tid; i < 1024; i += 256) {
        int r = i >> 5, c4 = i & 31;
        int node = n0 + r;
        float4 v = (node < n) ? *(const float4*)(h + (size_t)node * 128 + c4 * 4)
                              : make_float4(0.f, 0.f, 0.f, 0.f);
        *(float4*)&Hs[r][c4 * 4] = v;
    }
    __syncthreads();
    int r = tid >> 3;
    int node = n0 + r;
    int j0 = (tid & 7) * 4;
    if (node < n) {
        float a0 = bp[j0], a1 = bp[j0 + 1], a2 = bp[j0 + 2], a3 = bp[j0 + 3];
        #pragma unroll
        for (int k = 0; k < 128; k++) {
            float av = Hs[r][k];
            float4 w = *(const float4*)&Ws[k * 32 + j0];
            a0 += av * w.x; a1 += av * w.y; a2 += av * w.z; a3 += av * w.w;
        }
        *(float4*)(hp + (size_t)node * 32 + j0) = make_float4(a0, a1, a2, a3);
    }
}

// ---------------- pair predictor MLP ----------------
__global__ __launch_bounds__(256) void predictor_k(const float* __restrict__ hp,
                                                   const int* __restrict__ ps, const int* __restrict__ pd,
                                                   const int* __restrict__ ns, const int* __restrict__ nd,
                                                   const float* __restrict__ Wq1, const float* __restrict__ bq1,
                                                   const float* __restrict__ Wq2, const float* __restrict__ bq2,
                                                   const float* __restrict__ Wq3, const float* __restrict__ bq3,
                                                   float* __restrict__ out, int P) {
    __shared__ float w1[1024], w2[1024], w3[32], b1[32], b2[32];
    int tid = threadIdx.x;
    for (int i = tid; i < 1024; i += 256) { w1[i] = Wq1[i]; w2[i] = Wq2[i]; }
    if (tid < 32) { w3[tid] = Wq3[tid]; b1[tid] = bq1[tid]; b2[tid] = bq2[tid]; }
    __syncthreads();
    int gid = blockIdx.x * 256 + tid;
    if (gid >= 2 * P) return;
    int i = (gid < P) ? gid : gid - P;
    int a = (gid < P) ? ps[i] : ns[i];
    int b = (gid < P) ? pd[i] : nd[i];
    float z[32];
    const float4* ha = (const float4*)(hp + (size_t)a * 32);
    const float4* hb = (const float4*)(hp + (size_t)b * 32);
    #pragma unroll
    for (int q = 0; q < 8; q++) {
        float4 x = ha[q], y = hb[q];
        z[q * 4 + 0] = x.x * y.x; z[q * 4 + 1] = x.y * y.y;
        z[q * 4 + 2] = x.z * y.z; z[q * 4 + 3] = x.w * y.w;
    }
    float z1[32];
    #pragma unroll
    for (int j = 0; j < 32; j++) {
        float s = b1[j];
        #pragma unroll
        for (int k = 0; k < 32; k++) s += z[k] * w1[k * 32 + j];
        z1[j] = fmaxf(s, 0.f);
    }
    #pragma unroll
    for (int j = 0; j < 32; j++) {
        float s = b2[j];
        #pragma unroll
        for (int k = 0; k < 32; k++) s += z1[k] * w2[k * 32 + j];
        z[j] = fmaxf(s, 0.f);
    }
    float s3 = bq3[0];
    #pragma unroll
    for (int j = 0; j < 32; j++) s3 += z[j] * w3[j];
    out[gid] = s3;
}

// ---------------- launch ----------------
extern "C" void kernel_launch(void* const* d_in, const int* in_sizes, int n_in,
                              void* d_out, int out_size, void* d_ws, size_t ws_size,
                              hipStream_t stream) {
    const float* x   = (const float*)d_in[0];
    const int* src   = (const int*)d_in[1];
    const int* dst   = (const int*)d_in[2];
    const int* psrc  = (const int*)d_in[3];
    const int* pdst  = (const int*)d_in[4];
    const int* nsrc  = (const int*)d_in[5];
    const int* ndst  = (const int*)d_in[6];
    const float* W[3]  = { (const float*)d_in[7],  (const float*)d_in[11], (const float*)d_in[15] };
    const float* al[3] = { (const float*)d_in[8],  (const float*)d_in[12], (const float*)d_in[16] };
    const float* ar[3] = { (const float*)d_in[9],  (const float*)d_in[13], (const float*)d_in[17] };
    const float* bb[3] = { (const float*)d_in[10], (const float*)d_in[14], (const float*)d_in[18] };
    const float* Wp  = (const float*)d_in[19];
    const float* bp  = (const float*)d_in[20];
    const float* Wq1 = (const float*)d_in[21];
    const float* bq1 = (const float*)d_in[22];
    const float* Wq2 = (const float*)d_in[23];
    const float* bq2 = (const float*)d_in[24];
    const float* Wq3 = (const float*)d_in[25];
    const float* bq3 = (const float*)d_in[26];
    float* out = (float*)d_out;

    const int N = in_sizes[0] / 128;
    const int E = in_sizes[1];
    const int P = in_sizes[3];

    size_t off = 0;
    auto alloc = [&](size_t bytes) {
        void* p = (char*)d_ws + off;
        off += (bytes + 255) & ~(size_t)255;
        return p;
    };
    float* bufF  = (float*)alloc((size_t)N * 128 * 4);
    float* bufH  = (float*)alloc((size_t)N * 128 * 4);
    float* elA   = (float*)alloc((size_t)N * 4 * 4);
    float* erA   = (float*)alloc((size_t)N * 4 * 4);
    float* hp    = (float*)alloc((size_t)N * 32 * 4);
    int* rowptr  = (int*)alloc((size_t)(N + 1) * 4);
    int* csrc    = (int*)alloc((size_t)E * 4);
    int* cdst    = (int*)alloc((size_t)E * 4);
    float* wbuf  = (float*)alloc((size_t)E * 4 * 4);
    int* deg     = (int*)alloc((size_t)N * 4);
    int* cursor  = (int*)alloc((size_t)N * 4);
    int* bsum    = (int*)alloc(1024 * 4);
    (void)ws_size;

    const int NB_E = (E + 255) / 256;
    const int NB_N = (N + 255) / 256;

    hipMemsetAsync(deg, 0, (size_t)N * 4, stream);
    hipMemsetAsync(cursor, 0, (size_t)N * 4, stream);

    hist_k<<<NB_E, 256, 0, stream>>>(dst, deg, E);
    scan1_k<<<NB_N, 256, 0, stream>>>(deg, rowptr, bsum, N);
    scan2_k<<<1, 512, 0, stream>>>(bsum, NB_N);
    scan3_k<<<NB_N, 256, 0, stream>>>(rowptr, bsum, N);
    fill_k<<<NB_E, 256, 0, stream>>>(src, dst, rowptr, cursor, csrc, cdst, E);

    const int GEMM_B = (N + 63) / 64;
    const float* hin = x;
    for (int l = 0; l < 3; l++) {
        gemm_feat_k<<<GEMM_B, 128, 0, stream>>>(hin, W[l], al[l], ar[l], bufF, elA, erA, N);
        edgew_k<<<NB_E, 256, 0, stream>>>(csrc, cdst, elA, erA, wbuf, E);
        aggregate_k<<<(N + 3) / 4, 256, 0, stream>>>(bufF, wbuf, rowptr, csrc, bb[l], bufH, N);
        hin = bufH;
    }
    proj_k<<<(N + 31) / 32, 256, 0, stream>>>(bufH, Wp, bp, hp, N);
    predictor_k<<<(2 * P + 255) / 256, 256, 0, stream>>>(hp, psrc, pdst, nsrc, ndst,
                                                         Wq1, bq1, Wq2, bq2, Wq3, bq3, out, P);
}

// Round 6
// 593.903 us; speedup vs baseline: 1.7918x; 1.7918x over previous
//
#include <hip/hip_runtime.h>
#include <math.h>

// ---------------- CSR build ----------------
__global__ __launch_bounds__(256) void hist_k(const int* __restrict__ dst, int* __restrict__ deg, int e) {
    int i = blockIdx.x * 256 + threadIdx.x;
    if (i < e) atomicAdd(&deg[dst[i]], 1);
}

__global__ __launch_bounds__(256) void scan1_k(const int* __restrict__ deg, int* __restrict__ rowptr,
                                               int* __restrict__ bsum, int n) {
    __shared__ int sh[256];
    int tid = threadIdx.x;
    int sid = blockIdx.x * 256 + tid;
    int v = (sid < n) ? deg[sid] : 0;
    sh[tid] = v; __syncthreads();
    for (int off = 1; off < 256; off <<= 1) {
        int t = (tid >= off) ? sh[tid - off] : 0;
        __syncthreads();
        sh[tid] += t;
        __syncthreads();
    }
    if (sid < n) rowptr[sid + 1] = sh[tid];
    if (tid == 255) bsum[blockIdx.x] = sh[255];
}

__global__ __launch_bounds__(512) void scan2_k(int* __restrict__ bsum, int nb) {
    __shared__ int sh[512];
    int tid = threadIdx.x;
    sh[tid] = (tid < nb) ? bsum[tid] : 0;
    __syncthreads();
    for (int off = 1; off < 512; off <<= 1) {
        int t = (tid >= off) ? sh[tid - off] : 0;
        __syncthreads();
        sh[tid] += t;
        __syncthreads();
    }
    if (tid < nb) bsum[tid] = sh[tid];
}

__global__ __launch_bounds__(256) void scan3_k(int* __restrict__ rowptr, const int* __restrict__ bsum, int n) {
    int sid = blockIdx.x * 256 + threadIdx.x;
    if (sid == 0) rowptr[0] = 0;
    if (sid < n && blockIdx.x > 0) rowptr[sid + 1] += bsum[blockIdx.x - 1];
}

__global__ __launch_bounds__(256) void fill_k(const int* __restrict__ src, const int* __restrict__ dst,
                                              const int* __restrict__ rowptr, int* __restrict__ cursor,
                                              int* __restrict__ csrc, int* __restrict__ cdst, int e) {
    int i = blockIdx.x * 256 + threadIdx.x;
    if (i < e) {
        int d = dst[i];
        int pos = rowptr[d] + atomicAdd(&cursor[d], 1);
        csrc[pos] = src[i];
        cdst[pos] = d;
    }
}

// ---------------- fp32 GEMM: C[M,128] = A[M,128] @ W[128,128], fused el/er ----------------
// BM=64, 256 threads (4 waves), 4x8 micro-tile, register-prefetch double buffering.
// ~80 VGPRs -> no spill (round-5 lesson: launch_bounds(128,3) forced an 84-reg cap
// on a ~112-reg kernel -> 500 MB scratch traffic). No min-waves spec here.
__global__ __launch_bounds__(256) void gemm_feat_k(const float* __restrict__ A, const float* __restrict__ W,
                                                   const float* __restrict__ al, const float* __restrict__ ar,
                                                   float* __restrict__ C, float* __restrict__ el,
                                                   float* __restrict__ er, int M) {
    __shared__ float As[32][65];    // [k][m] transposed; stride 65 -> <=2 lanes/bank on transpose stores
    __shared__ float Bs[32][128];   // [k][n]
    int tid = threadIdx.x;
    int m0 = blockIdx.x * 64;
    int tr = tid >> 4;        // 0..15 -> rows tr*4 .. tr*4+3
    int tc = tid & 15;        // cols tc*4..+3 and 64+tc*4..+3
    float4 alA = *(const float4*)(al + tc * 4);
    float4 alB = *(const float4*)(al + 64 + tc * 4);
    float4 arA = *(const float4*)(ar + tc * 4);
    float4 arB = *(const float4*)(ar + 64 + tc * 4);
    float acc[4][8];
    #pragma unroll
    for (int i = 0; i < 4; i++)
        #pragma unroll
        for (int j = 0; j < 8; j++) acc[i][j] = 0.f;

    // A-load: 64 rows x 32 k per block; two row-passes of (32 rows x 8 lanes x float4)
    int arow = tid >> 3, akc = tid & 7;   // rows 0..31 (+32 on pass 2), k-chunk 0..7
    // B-load: 32 k-rows x 128 cols; 4 passes of (8 k-rows x 32 col-chunks)
    int bkr = tid >> 5, bcg = tid & 31;

    int mmA = min(m0 + arow, M - 1);
    int mmB = min(m0 + 32 + arow, M - 1);
    const float* ArowA = A + (size_t)mmA * 128;
    const float* ArowB = A + (size_t)mmB * 128;

    float4 pa[2], pb[4];
    #pragma unroll
    for (int j = 0; j < 2; j++)
        pa[j] = *(const float4*)((j ? ArowB : ArowA) + akc * 4);
    #pragma unroll
    for (int rp = 0; rp < 4; rp++)
        pb[rp] = *(const float4*)(W + (size_t)(rp * 8 + bkr) * 128 + bcg * 4);

    for (int kb = 0; kb < 128; kb += 32) {
        // write prefetched regs to LDS (transpose A)
        #pragma unroll
        for (int j = 0; j < 2; j++) {
            int r = arow + j * 32;
            As[akc * 4 + 0][r] = pa[j].x;
            As[akc * 4 + 1][r] = pa[j].y;
            As[akc * 4 + 2][r] = pa[j].z;
            As[akc * 4 + 3][r] = pa[j].w;
        }
        #pragma unroll
        for (int rp = 0; rp < 4; rp++)
            *(float4*)&Bs[rp * 8 + bkr][bcg * 4] = pb[rp];
        __syncthreads();
        // issue next k-block's global loads; consumed at next LDS write,
        // so HBM/L2 latency hides under the 32-step compute below
        if (kb < 96) {
            int kn = kb + 32;
            #pragma unroll
            for (int j = 0; j < 2; j++)
                pa[j] = *(const float4*)((j ? ArowB : ArowA) + kn + akc * 4);
            #pragma unroll
            for (int rp = 0; rp < 4; rp++)
                pb[rp] = *(const float4*)(W + (size_t)(kn + rp * 8 + bkr) * 128 + bcg * 4);
        }
        #pragma unroll
        for (int k = 0; k < 32; ++k) {
            float a[4], b[8];
            *(float4*)(a)     = *(float4*)&As[k][tr * 4];
            *(float4*)(b)     = *(float4*)&Bs[k][tc * 4];
            *(float4*)(b + 4) = *(float4*)&Bs[k][64 + tc * 4];
            #pragma unroll
            for (int i = 0; i < 4; i++)
                #pragma unroll
                for (int j = 0; j < 8; j++) acc[i][j] += a[i] * b[j];
        }
        __syncthreads();
    }
    // store C
    #pragma unroll
    for (int i = 0; i < 4; i++) {
        int m = m0 + tr * 4 + i;
        if (m < M) {
            *(float4*)(C + (size_t)m * 128 + tc * 4)      = make_float4(acc[i][0], acc[i][1], acc[i][2], acc[i][3]);
            *(float4*)(C + (size_t)m * 128 + 64 + tc * 4) = make_float4(acc[i][4], acc[i][5], acc[i][6], acc[i][7]);
        }
    }
    // fused el/er: per-head dot partials, reduced across the 8 lanes sharing tc&7
    #pragma unroll
    for (int i = 0; i < 4; i++) {
        float plA = acc[i][0] * alA.x + acc[i][1] * alA.y + acc[i][2] * alA.z + acc[i][3] * alA.w;
        float plB = acc[i][4] * alB.x + acc[i][5] * alB.y + acc[i][6] * alB.z + acc[i][7] * alB.w;
        float prA = acc[i][0] * arA.x + acc[i][1] * arA.y + acc[i][2] * arA.z + acc[i][3] * arA.w;
        float prB = acc[i][4] * arB.x + acc[i][5] * arB.y + acc[i][6] * arB.z + acc[i][7] * arB.w;
        #pragma unroll
        for (int off = 1; off < 8; off <<= 1) {
            plA += __shfl_xor(plA, off);
            plB += __shfl_xor(plB, off);
            prA += __shfl_xor(prA, off);
            prB += __shfl_xor(prB, off);
        }
        if ((tc & 7) == 0) {
            int m = m0 + tr * 4 + i;
            if (m < M) {
                int hA = tc >> 3;
                el[m * 4 + hA]     = plA;
                el[m * 4 + hA + 2] = plB;
                er[m * 4 + hA]     = prA;
                er[m * 4 + hA + 2] = prB;
            }
        }
    }
}

// ---------------- per-edge attention weights (CSR order, coalesced) ----------------
__global__ __launch_bounds__(256) void edgew_k(const int* __restrict__ csrc, const int* __restrict__ cdst,
                                               const float* __restrict__ el, const float* __restrict__ er,
                                               float* __restrict__ wbuf, int e) {
    int p = blockIdx.x * 256 + threadIdx.x;
    if (p >= e) return;
    int s = csrc[p], d = cdst[p];
    float4 l4 = *(const float4*)(el + (size_t)s * 4);
    float4 r4 = *(const float4*)(er + (size_t)d * 4);
    float e0 = l4.x + r4.x, e1 = l4.y + r4.y, e2 = l4.z + r4.z, e3 = l4.w + r4.w;
    e0 = (e0 > 0.f) ? e0 : 0.2f * e0;
    e1 = (e1 > 0.f) ? e1 : 0.2f * e1;
    e2 = (e2 > 0.f) ? e2 : 0.2f * e2;
    e3 = (e3 > 0.f) ? e3 : 0.2f * e3;
    *(float4*)(wbuf + (size_t)p * 4) = make_float4(__expf(e0), __expf(e1), __expf(e2), __expf(e3));
}

// ---------------- per-node aggregate + bias + ELU ----------------
__global__ __launch_bounds__(256) void aggregate_k(const float* __restrict__ feat, const float* __restrict__ wbuf,
                                                   const int* __restrict__ rowptr, const int* __restrict__ csrc,
                                                   const float* __restrict__ bias, float* __restrict__ out, int n) {
    int wid = threadIdx.x >> 6;
    int lane = threadIdx.x & 63;
    int node = blockIdx.x * 4 + wid;
    if (node >= n) return;
    int h = lane >> 4;
    int p0 = rowptr[node], p1 = rowptr[node + 1];
    float2 b2 = *(const float2*)(bias + lane * 2);
    float lsum = 0.f, a0 = 0.f, a1 = 0.f;
    int p = p0;
    for (; p + 4 <= p1; p += 4) {
        int s0 = csrc[p], s1 = csrc[p + 1], s2 = csrc[p + 2], s3 = csrc[p + 3];
        float w0 = wbuf[(size_t)p * 4 + h];
        float w1 = wbuf[(size_t)(p + 1) * 4 + h];
        float w2 = wbuf[(size_t)(p + 2) * 4 + h];
        float w3 = wbuf[(size_t)(p + 3) * 4 + h];
        float2 f0 = *(const float2*)(feat + (size_t)s0 * 128 + lane * 2);
        float2 f1 = *(const float2*)(feat + (size_t)s1 * 128 + lane * 2);
        float2 f2 = *(const float2*)(feat + (size_t)s2 * 128 + lane * 2);
        float2 f3 = *(const float2*)(feat + (size_t)s3 * 128 + lane * 2);
        lsum += (w0 + w1) + (w2 + w3);
        a0 += w0 * f0.x + w1 * f1.x + w2 * f2.x + w3 * f3.x;
        a1 += w0 * f0.y + w1 * f1.y + w2 * f2.y + w3 * f3.y;
    }
    for (; p < p1; ++p) {
        int s = csrc[p];
        float w = wbuf[(size_t)p * 4 + h];
        float2 f = *(const float2*)(feat + (size_t)s * 128 + lane * 2);
        lsum += w;
        a0 += w * f.x;
        a1 += w * f.y;
    }
    float inv = 1.f / fmaxf(lsum, 1e-9f);
    float v0 = a0 * inv + b2.x;
    float v1 = a1 * inv + b2.y;
    v0 = (v0 > 0.f) ? v0 : expm1f(v0);
    v1 = (v1 > 0.f) ? v1 : expm1f(v1);
    *(float2*)(out + (size_t)node * 128 + lane * 2) = make_float2(v0, v1);
}

// ---------------- projection: hp[N,32] = h[N,128] @ Wp[128,32] + bp ----------------
__global__ __launch_bounds__(256) void proj_k(const float* __restrict__ h, const float* __restrict__ Wp,
                                              const float* __restrict__ bp, float* __restrict__ hp, int n) {
    __shared__ float Ws[128 * 32];
    __shared__ float Hs[32][132];
    int tid = threadIdx.x;
    for (int i = tid; i < 4096; i += 256) Ws[i] = Wp[i];
    int n0 = blockIdx.x * 32;
    for (int i = tid; i < 1024; i += 256) {
        int r = i >> 5, c4 = i & 31;
        int node = n0 + r;
        float4 v = (node < n) ? *(const float4*)(h + (size_t)node * 128 + c4 * 4)
                              : make_float4(0.f, 0.f, 0.f, 0.f);
        *(float4*)&Hs[r][c4 * 4] = v;
    }
    __syncthreads();
    int r = tid >> 3;
    int node = n0 + r;
    int j0 = (tid & 7) * 4;
    if (node < n) {
        float a0 = bp[j0], a1 = bp[j0 + 1], a2 = bp[j0 + 2], a3 = bp[j0 + 3];
        #pragma unroll
        for (int k = 0; k < 128; k++) {
            float av = Hs[r][k];
            float4 w = *(const float4*)&Ws[k * 32 + j0];
            a0 += av * w.x; a1 += av * w.y; a2 += av * w.z; a3 += av * w.w;
        }
        *(float4*)(hp + (size_t)node * 32 + j0) = make_float4(a0, a1, a2, a3);
    }
}

// ---------------- pair predictor MLP ----------------
__global__ __launch_bounds__(256) void predictor_k(const float* __restrict__ hp,
                                                   const int* __restrict__ ps, const int* __restrict__ pd,
                                                   const int* __restrict__ ns, const int* __restrict__ nd,
                                                   const float* __restrict__ Wq1, const float* __restrict__ bq1,
                                                   const float* __restrict__ Wq2, const float* __restrict__ bq2,
                                                   const float* __restrict__ Wq3, const float* __restrict__ bq3,
                                                   float* __restrict__ out, int P) {
    __shared__ float w1[1024], w2[1024], w3[32], b1[32], b2[32];
    int tid = threadIdx.x;
    for (int i = tid; i < 1024; i += 256) { w1[i] = Wq1[i]; w2[i] = Wq2[i]; }
    if (tid < 32) { w3[tid] = Wq3[tid]; b1[tid] = bq1[tid]; b2[tid] = bq2[tid]; }
    __syncthreads();
    int gid = blockIdx.x * 256 + tid;
    if (gid >= 2 * P) return;
    int i = (gid < P) ? gid : gid - P;
    int a = (gid < P) ? ps[i] : ns[i];
    int b = (gid < P) ? pd[i] : nd[i];
    float z[32];
    const float4* ha = (const float4*)(hp + (size_t)a * 32);
    const float4* hb = (const float4*)(hp + (size_t)b * 32);
    #pragma unroll
    for (int q = 0; q < 8; q++) {
        float4 x = ha[q], y = hb[q];
        z[q * 4 + 0] = x.x * y.x; z[q * 4 + 1] = x.y * y.y;
        z[q * 4 + 2] = x.z * y.z; z[q * 4 + 3] = x.w * y.w;
    }
    float z1[32];
    #pragma unroll
    for (int j = 0; j < 32; j++) {
        float s = b1[j];
        #pragma unroll
        for (int k = 0; k < 32; k++) s += z[k] * w1[k * 32 + j];
        z1[j] = fmaxf(s, 0.f);
    }
    #pragma unroll
    for (int j = 0; j < 32; j++) {
        float s = b2[j];
        #pragma unroll
        for (int k = 0; k < 32; k++) s += z1[k] * w2[k * 32 + j];
        z[j] = fmaxf(s, 0.f);
    }
    float s3 = bq3[0];
    #pragma unroll
    for (int j = 0; j < 32; j++) s3 += z[j] * w3[j];
    out[gid] = s3;
}

// ---------------- launch ----------------
extern "C" void kernel_launch(void* const* d_in, const int* in_sizes, int n_in,
                              void* d_out, int out_size, void* d_ws, size_t ws_size,
                              hipStream_t stream) {
    const float* x   = (const float*)d_in[0];
    const int* src   = (const int*)d_in[1];
    const int* dst   = (const int*)d_in[2];
    const int* psrc  = (const int*)d_in[3];
    const int* pdst  = (const int*)d_in[4];
    const int* nsrc  = (const int*)d_in[5];
    const int* ndst  = (const int*)d_in[6];
    const float* W[3]  = { (const float*)d_in[7],  (const float*)d_in[11], (const float*)d_in[15] };
    const float* al[3] = { (const float*)d_in[8],  (const float*)d_in[12], (const float*)d_in[16] };
    const float* ar[3] = { (const float*)d_in[9],  (const float*)d_in[13], (const float*)d_in[17] };
    const float* bb[3] = { (const float*)d_in[10], (const float*)d_in[14], (const float*)d_in[18] };
    const float* Wp  = (const float*)d_in[19];
    const float* bp  = (const float*)d_in[20];
    const float* Wq1 = (const float*)d_in[21];
    const float* bq1 = (const float*)d_in[22];
    const float* Wq2 = (const float*)d_in[23];
    const float* bq2 = (const float*)d_in[24];
    const float* Wq3 = (const float*)d_in[25];
    const float* bq3 = (const float*)d_in[26];
    float* out = (float*)d_out;

    const int N = in_sizes[0] / 128;
    const int E = in_sizes[1];
    const int P = in_sizes[3];

    size_t off = 0;
    auto alloc = [&](size_t bytes) {
        void* p = (char*)d_ws + off;
        off += (bytes + 255) & ~(size_t)255;
        return p;
    };
    float* bufF  = (float*)alloc((size_t)N * 128 * 4);
    float* bufH  = (float*)alloc((size_t)N * 128 * 4);
    float* elA   = (float*)alloc((size_t)N * 4 * 4);
    float* erA   = (float*)alloc((size_t)N * 4 * 4);
    float* hp    = (float*)alloc((size_t)N * 32 * 4);
    int* rowptr  = (int*)alloc((size_t)(N + 1) * 4);
    int* csrc    = (int*)alloc((size_t)E * 4);
    int* cdst    = (int*)alloc((size_t)E * 4);
    float* wbuf  = (float*)alloc((size_t)E * 4 * 4);
    int* deg     = (int*)alloc((size_t)N * 4);
    int* cursor  = (int*)alloc((size_t)N * 4);
    int* bsum    = (int*)alloc(1024 * 4);
    (void)ws_size;

    const int NB_E = (E + 255) / 256;
    const int NB_N = (N + 255) / 256;

    hipMemsetAsync(deg, 0, (size_t)N * 4, stream);
    hipMemsetAsync(cursor, 0, (size_t)N * 4, stream);

    hist_k<<<NB_E, 256, 0, stream>>>(dst, deg, E);
    scan1_k<<<NB_N, 256, 0, stream>>>(deg, rowptr, bsum, N);
    scan2_k<<<1, 512, 0, stream>>>(bsum, NB_N);
    scan3_k<<<NB_N, 256, 0, stream>>>(rowptr, bsum, N);
    fill_k<<<NB_E, 256, 0, stream>>>(src, dst, rowptr, cursor, csrc, cdst, E);

    const int GEMM_B = (N + 63) / 64;
    const float* hin = x;
    for (int l = 0; l < 3; l++) {
        gemm_feat_k<<<GEMM_B, 256, 0, stream>>>(hin, W[l], al[l], ar[l], bufF, elA, erA, N);
        edgew_k<<<NB_E, 256, 0, stream>>>(csrc, cdst, elA, erA, wbuf, E);
        aggregate_k<<<(N + 3) / 4, 256, 0, stream>>>(bufF, wbuf, rowptr, csrc, bb[l], bufH, N);
        hin = bufH;
    }
    proj_k<<<(N + 31) / 32, 256, 0, stream>>>(bufH, Wp, bp, hp, N);
    predictor_k<<<(2 * P + 255) / 256, 256, 0, stream>>>(hp, psrc, pdst, nsrc, ndst,
                                                         Wq1, bq1, Wq2, bq2, Wq3, bq3, out, P);
}

// Round 7
// 557.478 us; speedup vs baseline: 1.9088x; 1.0653x over previous
//
#include <hip/hip_runtime.h>
#include <math.h>

typedef __attribute__((ext_vector_type(8))) short bf16x8;
typedef __attribute__((ext_vector_type(4))) float f32x4;

__device__ __forceinline__ unsigned short f2bf_rtne(float v) {
    unsigned u = __float_as_uint(v);
    u += 0x7FFFu + ((u >> 16) & 1u);
    return (unsigned short)(u >> 16);
}

// ---------------- CSR build ----------------
__global__ __launch_bounds__(256) void hist_k(const int* __restrict__ dst, int* __restrict__ deg, int e) {
    int i = blockIdx.x * 256 + threadIdx.x;
    if (i < e) atomicAdd(&deg[dst[i]], 1);
}

__global__ __launch_bounds__(256) void scan1_k(const int* __restrict__ deg, int* __restrict__ rowptr,
                                               int* __restrict__ bsum, int n) {
    __shared__ int sh[256];
    int tid = threadIdx.x;
    int sid = blockIdx.x * 256 + tid;
    int v = (sid < n) ? deg[sid] : 0;
    sh[tid] = v; __syncthreads();
    for (int off = 1; off < 256; off <<= 1) {
        int t = (tid >= off) ? sh[tid - off] : 0;
        __syncthreads();
        sh[tid] += t;
        __syncthreads();
    }
    if (sid < n) rowptr[sid + 1] = sh[tid];
    if (tid == 255) bsum[blockIdx.x] = sh[255];
}

__global__ __launch_bounds__(512) void scan2_k(int* __restrict__ bsum, int nb) {
    __shared__ int sh[512];
    int tid = threadIdx.x;
    sh[tid] = (tid < nb) ? bsum[tid] : 0;
    __syncthreads();
    for (int off = 1; off < 512; off <<= 1) {
        int t = (tid >= off) ? sh[tid - off] : 0;
        __syncthreads();
        sh[tid] += t;
        __syncthreads();
    }
    if (tid < nb) bsum[tid] = sh[tid];
}

__global__ __launch_bounds__(256) void scan3_k(int* __restrict__ rowptr, const int* __restrict__ bsum, int n) {
    int sid = blockIdx.x * 256 + threadIdx.x;
    if (sid == 0) rowptr[0] = 0;
    if (sid < n && blockIdx.x > 0) rowptr[sid + 1] += bsum[blockIdx.x - 1];
}

__global__ __launch_bounds__(256) void fill_k(const int* __restrict__ src, const int* __restrict__ dst,
                                              const int* __restrict__ rowptr, int* __restrict__ cursor,
                                              int* __restrict__ csrc, int* __restrict__ cdst, int e) {
    int i = blockIdx.x * 256 + threadIdx.x;
    if (i < e) {
        int d = dst[i];
        int pos = rowptr[d] + atomicAdd(&cursor[d], 1);
        csrc[pos] = src[i];
        cdst[pos] = d;
    }
}

// ---------------- W -> transposed hi/lo bf16 ([n][k] layout) ----------------
__global__ __launch_bounds__(256) void wconv_k(const float* __restrict__ W,
                                               unsigned short* __restrict__ Wth,
                                               unsigned short* __restrict__ Wtl) {
    int idx = blockIdx.x * 256 + threadIdx.x;    // 0..16383
    int k = idx >> 7, n = idx & 127;
    float v = W[idx];
    unsigned short h = f2bf_rtne(v);
    float hf = __uint_as_float((unsigned)h << 16);
    Wth[n * 128 + k] = h;
    Wtl[n * 128 + k] = f2bf_rtne(v - hf);
}

// ---------------- split-bf16 MFMA GEMM: C[M,128] = A @ W, fused el/er ----------------
// A*W ~= Ah*Wh + Ah*Wl + Al*Wh  (hi/lo bf16 split, ~17 mantissa bits -> ~2^-18 rel err).
// Per block: 128 rows, 4 waves, wave w owns rows w*32..+31 as 2 M-frags x 8 N-frags
// of mfma_f32_16x16x32_bf16. No LDS, no barriers; all 782 blocks co-resident.
__global__ __launch_bounds__(256) void gemm_mfma_k(const float* __restrict__ A,
        const unsigned short* __restrict__ Wth, const unsigned short* __restrict__ Wtl,
        const float* __restrict__ alp, const float* __restrict__ arp,
        float* __restrict__ C, float* __restrict__ el, float* __restrict__ er, int M) {
    int tid = threadIdx.x;
    int wv = tid >> 6, lane = tid & 63;
    int l15 = lane & 15, lhi = lane >> 4;
    int mb = blockIdx.x * 128 + wv * 32;

    f32x4 acc[2][8];
    #pragma unroll
    for (int f = 0; f < 2; f++)
        #pragma unroll
        for (int n = 0; n < 8; n++) acc[f][n] = (f32x4){0.f, 0.f, 0.f, 0.f};

    float alv[8], arv[8];
    #pragma unroll
    for (int n = 0; n < 8; n++) { alv[n] = alp[n * 16 + l15]; arv[n] = arp[n * 16 + l15]; }

    int r0 = mb + l15, r1 = mb + 16 + l15;
    const float* a0p = A + (size_t)min(r0, M - 1) * 128 + lhi * 8;
    const float* a1p = A + (size_t)min(r1, M - 1) * 128 + lhi * 8;

    #pragma unroll
    for (int ks = 0; ks < 4; ks++) {
        int kb = ks * 32 + lhi * 8;
        float av[8];
        bf16x8 a0h, a0l, a1h, a1l;
        *(float4*)(av)     = *(const float4*)(a0p + ks * 32);
        *(float4*)(av + 4) = *(const float4*)(a0p + ks * 32 + 4);
        #pragma unroll
        for (int j = 0; j < 8; j++) {
            unsigned short h = f2bf_rtne(av[j]);
            a0h[j] = (short)h;
            a0l[j] = (short)f2bf_rtne(av[j] - __uint_as_float((unsigned)h << 16));
        }
        *(float4*)(av)     = *(const float4*)(a1p + ks * 32);
        *(float4*)(av + 4) = *(const float4*)(a1p + ks * 32 + 4);
        #pragma unroll
        for (int j = 0; j < 8; j++) {
            unsigned short h = f2bf_rtne(av[j]);
            a1h[j] = (short)h;
            a1l[j] = (short)f2bf_rtne(av[j] - __uint_as_float((unsigned)h << 16));
        }
        #pragma unroll
        for (int n = 0; n < 8; n++) {
            bf16x8 bhv = *(const bf16x8*)(Wth + (size_t)(n * 16 + l15) * 128 + kb);
            bf16x8 blv = *(const bf16x8*)(Wtl + (size_t)(n * 16 + l15) * 128 + kb);
            acc[0][n] = __builtin_amdgcn_mfma_f32_16x16x32_bf16(a0h, bhv, acc[0][n], 0, 0, 0);
            acc[1][n] = __builtin_amdgcn_mfma_f32_16x16x32_bf16(a1h, bhv, acc[1][n], 0, 0, 0);
            acc[0][n] = __builtin_amdgcn_mfma_f32_16x16x32_bf16(a0l, bhv, acc[0][n], 0, 0, 0);
            acc[1][n] = __builtin_amdgcn_mfma_f32_16x16x32_bf16(a1l, bhv, acc[1][n], 0, 0, 0);
            acc[0][n] = __builtin_amdgcn_mfma_f32_16x16x32_bf16(a0h, blv, acc[0][n], 0, 0, 0);
            acc[1][n] = __builtin_amdgcn_mfma_f32_16x16x32_bf16(a1h, blv, acc[1][n], 0, 0, 0);
        }
    }

    // epilogue: C store + fused per-head el/er (D layout: row=(lane>>4)*4+i, col=lane&15)
    #pragma unroll
    for (int f = 0; f < 2; f++) {
        #pragma unroll
        for (int i = 0; i < 4; i++) {
            int r = mb + f * 16 + lhi * 4 + i;
            bool ok = (r < M);
            if (ok) {
                #pragma unroll
                for (int n = 0; n < 8; n++)
                    C[(size_t)r * 128 + n * 16 + l15] = acc[f][n][i];
            }
            float ph[4], qh[4];
            #pragma unroll
            for (int h = 0; h < 4; h++) {
                ph[h] = acc[f][2 * h][i] * alv[2 * h] + acc[f][2 * h + 1][i] * alv[2 * h + 1];
                qh[h] = acc[f][2 * h][i] * arv[2 * h] + acc[f][2 * h + 1][i] * arv[2 * h + 1];
            }
            #pragma unroll
            for (int off = 1; off < 16; off <<= 1) {
                #pragma unroll
                for (int h = 0; h < 4; h++) {
                    ph[h] += __shfl_xor(ph[h], off);
                    qh[h] += __shfl_xor(qh[h], off);
                }
            }
            if (ok && l15 < 8) {
                // static-index selects (avoid runtime-indexed reg array -> scratch)
                if (l15 < 4) {
                    float v = (l15 == 0) ? ph[0] : (l15 == 1) ? ph[1] : (l15 == 2) ? ph[2] : ph[3];
                    el[(size_t)r * 4 + l15] = v;
                } else {
                    int h = l15 - 4;
                    float v = (h == 0) ? qh[0] : (h == 1) ? qh[1] : (h == 2) ? qh[2] : qh[3];
                    er[(size_t)r * 4 + h] = v;
                }
            }
        }
    }
}

// ---------------- per-edge attention weights (CSR order, coalesced) ----------------
__global__ __launch_bounds__(256) void edgew_k(const int* __restrict__ csrc, const int* __restrict__ cdst,
                                               const float* __restrict__ el, const float* __restrict__ er,
                                               float* __restrict__ wbuf, int e) {
    int p = blockIdx.x * 256 + threadIdx.x;
    if (p >= e) return;
    int s = csrc[p], d = cdst[p];
    float4 l4 = *(const float4*)(el + (size_t)s * 4);
    float4 r4 = *(const float4*)(er + (size_t)d * 4);
    float e0 = l4.x + r4.x, e1 = l4.y + r4.y, e2 = l4.z + r4.z, e3 = l4.w + r4.w;
    e0 = (e0 > 0.f) ? e0 : 0.2f * e0;
    e1 = (e1 > 0.f) ? e1 : 0.2f * e1;
    e2 = (e2 > 0.f) ? e2 : 0.2f * e2;
    e3 = (e3 > 0.f) ? e3 : 0.2f * e3;
    *(float4*)(wbuf + (size_t)p * 4) = make_float4(__expf(e0), __expf(e1), __expf(e2), __expf(e3));
}

// ---------------- per-node aggregate + bias + ELU ----------------
__global__ __launch_bounds__(256) void aggregate_k(const float* __restrict__ feat, const float* __restrict__ wbuf,
                                                   const int* __restrict__ rowptr, const int* __restrict__ csrc,
                                                   const float* __restrict__ bias, float* __restrict__ out, int n) {
    int wid = threadIdx.x >> 6;
    int lane = threadIdx.x & 63;
    int node = blockIdx.x * 4 + wid;
    if (node >= n) return;
    int h = lane >> 4;
    int p0 = rowptr[node], p1 = rowptr[node + 1];
    float2 b2 = *(const float2*)(bias + lane * 2);
    float lsum = 0.f, a0 = 0.f, a1 = 0.f;
    int p = p0;
    for (; p + 4 <= p1; p += 4) {
        int s0 = csrc[p], s1 = csrc[p + 1], s2 = csrc[p + 2], s3 = csrc[p + 3];
        float w0 = wbuf[(size_t)p * 4 + h];
        float w1 = wbuf[(size_t)(p + 1) * 4 + h];
        float w2 = wbuf[(size_t)(p + 2) * 4 + h];
        float w3 = wbuf[(size_t)(p + 3) * 4 + h];
        float2 f0 = *(const float2*)(feat + (size_t)s0 * 128 + lane * 2);
        float2 f1 = *(const float2*)(feat + (size_t)s1 * 128 + lane * 2);
        float2 f2 = *(const float2*)(feat + (size_t)s2 * 128 + lane * 2);
        float2 f3 = *(const float2*)(feat + (size_t)s3 * 128 + lane * 2);
        lsum += (w0 + w1) + (w2 + w3);
        a0 += w0 * f0.x + w1 * f1.x + w2 * f2.x + w3 * f3.x;
        a1 += w0 * f0.y + w1 * f1.y + w2 * f2.y + w3 * f3.y;
    }
    for (; p < p1; ++p) {
        int s = csrc[p];
        float w = wbuf[(size_t)p * 4 + h];
        float2 f = *(const float2*)(feat + (size_t)s * 128 + lane * 2);
        lsum += w;
        a0 += w * f.x;
        a1 += w * f.y;
    }
    float inv = 1.f / fmaxf(lsum, 1e-9f);
    float v0 = a0 * inv + b2.x;
    float v1 = a1 * inv + b2.y;
    v0 = (v0 > 0.f) ? v0 : expm1f(v0);
    v1 = (v1 > 0.f) ? v1 : expm1f(v1);
    *(float2*)(out + (size_t)node * 128 + lane * 2) = make_float2(v0, v1);
}

// ---------------- projection: hp[N,32] = h[N,128] @ Wp[128,32] + bp ----------------
__global__ __launch_bounds__(256) void proj_k(const float* __restrict__ h, const float* __restrict__ Wp,
                                              const float* __restrict__ bp, float* __restrict__ hp, int n) {
    __shared__ float Ws[128 * 32];
    __shared__ float Hs[32][132];
    int tid = threadIdx.x;
    for (int i = tid; i < 4096; i += 256) Ws[i] = Wp[i];
    int n0 = blockIdx.x * 32;
    for (int i = tid; i < 1024; i += 256) {
        int r = i >> 5, c4 = i & 31;
        int node = n0 + r;
        float4 v = (node < n) ? *(const float4*)(h + (size_t)node * 128 + c4 * 4)
                              : make_float4(0.f, 0.f, 0.f, 0.f);
        *(float4*)&Hs[r][c4 * 4] = v;
    }
    __syncthreads();
    int r = tid >> 3;
    int node = n0 + r;
    int j0 = (tid & 7) * 4;
    if (node < n) {
        float a0 = bp[j0], a1 = bp[j0 + 1], a2 = bp[j0 + 2], a3 = bp[j0 + 3];
        #pragma unroll
        for (int k = 0; k < 128; k++) {
            float av = Hs[r][k];
            float4 w = *(const float4*)&Ws[k * 32 + j0];
            a0 += av * w.x; a1 += av * w.y; a2 += av * w.z; a3 += av * w.w;
        }
        *(float4*)(hp + (size_t)node * 32 + j0) = make_float4(a0, a1, a2, a3);
    }
}

// ---------------- pair predictor MLP ----------------
__global__ __launch_bounds__(256) void predictor_k(const float* __restrict__ hp,
                                                   const int* __restrict__ ps, const int* __restrict__ pd,
                                                   const int* __restrict__ ns, const int* __restrict__ nd,
                                                   const float* __restrict__ Wq1, const float* __restrict__ bq1,
                                                   const float* __restrict__ Wq2, const float* __restrict__ bq2,
                                                   const float* __restrict__ Wq3, const float* __restrict__ bq3,
                                                   float* __restrict__ out, int P) {
    __shared__ float w1[1024], w2[1024], w3[32], b1[32], b2[32];
    int tid = threadIdx.x;
    for (int i = tid; i < 1024; i += 256) { w1[i] = Wq1[i]; w2[i] = Wq2[i]; }
    if (tid < 32) { w3[tid] = Wq3[tid]; b1[tid] = bq1[tid]; b2[tid] = bq2[tid]; }
    __syncthreads();
    int gid = blockIdx.x * 256 + tid;
    if (gid >= 2 * P) return;
    int i = (gid < P) ? gid : gid - P;
    int a = (gid < P) ? ps[i] : ns[i];
    int b = (gid < P) ? pd[i] : nd[i];
    float z[32];
    const float4* ha = (const float4*)(hp + (size_t)a * 32);
    const float4* hb = (const float4*)(hp + (size_t)b * 32);
    #pragma unroll
    for (int q = 0; q < 8; q++) {
        float4 x = ha[q], y = hb[q];
        z[q * 4 + 0] = x.x * y.x; z[q * 4 + 1] = x.y * y.y;
        z[q * 4 + 2] = x.z * y.z; z[q * 4 + 3] = x.w * y.w;
    }
    float z1[32];
    #pragma unroll
    for (int j = 0; j < 32; j++) {
        float s = b1[j];
        #pragma unroll
        for (int k = 0; k < 32; k++) s += z[k] * w1[k * 32 + j];
        z1[j] = fmaxf(s, 0.f);
    }
    #pragma unroll
    for (int j = 0; j < 32; j++) {
        float s = b2[j];
        #pragma unroll
        for (int k = 0; k < 32; k++) s += z1[k] * w2[k * 32 + j];
        z[j] = fmaxf(s, 0.f);
    }
    float s3 = bq3[0];
    #pragma unroll
    for (int j = 0; j < 32; j++) s3 += z[j] * w3[j];
    out[gid] = s3;
}

// ---------------- launch ----------------
extern "C" void kernel_launch(void* const* d_in, const int* in_sizes, int n_in,
                              void* d_out, int out_size, void* d_ws, size_t ws_size,
                              hipStream_t stream) {
    const float* x   = (const float*)d_in[0];
    const int* src   = (const int*)d_in[1];
    const int* dst   = (const int*)d_in[2];
    const int* psrc  = (const int*)d_in[3];
    const int* pdst  = (const int*)d_in[4];
    const int* nsrc  = (const int*)d_in[5];
    const int* ndst  = (const int*)d_in[6];
    const float* W[3]  = { (const float*)d_in[7],  (const float*)d_in[11], (const float*)d_in[15] };
    const float* al[3] = { (const float*)d_in[8],  (const float*)d_in[12], (const float*)d_in[16] };
    const float* ar[3] = { (const float*)d_in[9],  (const float*)d_in[13], (const float*)d_in[17] };
    const float* bb[3] = { (const float*)d_in[10], (const float*)d_in[14], (const float*)d_in[18] };
    const float* Wp  = (const float*)d_in[19];
    const float* bp  = (const float*)d_in[20];
    const float* Wq1 = (const float*)d_in[21];
    const float* bq1 = (const float*)d_in[22];
    const float* Wq2 = (const float*)d_in[23];
    const float* bq2 = (const float*)d_in[24];
    const float* Wq3 = (const float*)d_in[25];
    const float* bq3 = (const float*)d_in[26];
    float* out = (float*)d_out;

    const int N = in_sizes[0] / 128;
    const int E = in_sizes[1];
    const int P = in_sizes[3];

    size_t off = 0;
    auto alloc = [&](size_t bytes) {
        void* p = (char*)d_ws + off;
        off += (bytes + 255) & ~(size_t)255;
        return p;
    };
    float* bufF  = (float*)alloc((size_t)N * 128 * 4);
    float* bufH  = (float*)alloc((size_t)N * 128 * 4);
    float* elA   = (float*)alloc((size_t)N * 4 * 4);
    float* erA   = (float*)alloc((size_t)N * 4 * 4);
    float* hp    = (float*)alloc((size_t)N * 32 * 4);
    int* rowptr  = (int*)alloc((size_t)(N + 1) * 4);
    int* csrc    = (int*)alloc((size_t)E * 4);
    int* cdst    = (int*)alloc((size_t)E * 4);
    float* wbuf  = (float*)alloc((size_t)E * 4 * 4);
    int* deg     = (int*)alloc((size_t)N * 4);
    int* cursor  = (int*)alloc((size_t)N * 4);
    int* bsum    = (int*)alloc(1024 * 4);
    unsigned short* Wth = (unsigned short*)alloc(16384 * 2);
    unsigned short* Wtl = (unsigned short*)alloc(16384 * 2);
    (void)ws_size;

    const int NB_E = (E + 255) / 256;
    const int NB_N = (N + 255) / 256;

    hipMemsetAsync(deg, 0, (size_t)N * 4, stream);
    hipMemsetAsync(cursor, 0, (size_t)N * 4, stream);

    hist_k<<<NB_E, 256, 0, stream>>>(dst, deg, E);
    scan1_k<<<NB_N, 256, 0, stream>>>(deg, rowptr, bsum, N);
    scan2_k<<<1, 512, 0, stream>>>(bsum, NB_N);
    scan3_k<<<NB_N, 256, 0, stream>>>(rowptr, bsum, N);
    fill_k<<<NB_E, 256, 0, stream>>>(src, dst, rowptr, cursor, csrc, cdst, E);

    const int GEMM_B = (N + 127) / 128;
    const float* hin = x;
    for (int l = 0; l < 3; l++) {
        wconv_k<<<64, 256, 0, stream>>>(W[l], Wth, Wtl);
        gemm_mfma_k<<<GEMM_B, 256, 0, stream>>>(hin, Wth, Wtl, al[l], ar[l], bufF, elA, erA, N);
        edgew_k<<<NB_E, 256, 0, stream>>>(csrc, cdst, elA, erA, wbuf, E);
        aggregate_k<<<(N + 3) / 4, 256, 0, stream>>>(bufF, wbuf, rowptr, csrc, bb[l], bufH, N);
        hin = bufH;
    }
    proj_k<<<(N + 31) / 32, 256, 0, stream>>>(bufH, Wp, bp, hp, N);
    predictor_k<<<(2 * P + 255) / 256, 256, 0, stream>>>(hp, psrc, pdst, nsrc, ndst,
                                                         Wq1, bq1, Wq2, bq2, Wq3, bq3, out, P);
}

// Round 8
// 507.640 us; speedup vs baseline: 2.0962x; 1.0982x over previous
//
#include <hip/hip_runtime.h>
#include <math.h>

typedef __attribute__((ext_vector_type(8))) short bf16x8;
typedef __attribute__((ext_vector_type(4))) float f32x4;

__device__ __forceinline__ unsigned short f2bf_rtne(float v) {
    unsigned u = __float_as_uint(v);
    u += 0x7FFFu + ((u >> 16) & 1u);
    return (unsigned short)(u >> 16);
}

// ---------------- CSR build ----------------
__global__ __launch_bounds__(256) void hist_k(const int* __restrict__ dst, int* __restrict__ deg, int e) {
    int i = blockIdx.x * 256 + threadIdx.x;
    if (i < e) atomicAdd(&deg[dst[i]], 1);
}

__global__ __launch_bounds__(256) void scan1_k(const int* __restrict__ deg, int* __restrict__ rowptr,
                                               int* __restrict__ bsum, int n) {
    __shared__ int sh[256];
    int tid = threadIdx.x;
    int sid = blockIdx.x * 256 + tid;
    int v = (sid < n) ? deg[sid] : 0;
    sh[tid] = v; __syncthreads();
    for (int off = 1; off < 256; off <<= 1) {
        int t = (tid >= off) ? sh[tid - off] : 0;
        __syncthreads();
        sh[tid] += t;
        __syncthreads();
    }
    if (sid < n) rowptr[sid + 1] = sh[tid];
    if (tid == 255) bsum[blockIdx.x] = sh[255];
}

__global__ __launch_bounds__(512) void scan2_k(int* __restrict__ bsum, int nb) {
    __shared__ int sh[512];
    int tid = threadIdx.x;
    sh[tid] = (tid < nb) ? bsum[tid] : 0;
    __syncthreads();
    for (int off = 1; off < 512; off <<= 1) {
        int t = (tid >= off) ? sh[tid - off] : 0;
        __syncthreads();
        sh[tid] += t;
        __syncthreads();
    }
    if (tid < nb) bsum[tid] = sh[tid];
}

__global__ __launch_bounds__(256) void scan3_k(int* __restrict__ rowptr, const int* __restrict__ bsum, int n) {
    int sid = blockIdx.x * 256 + threadIdx.x;
    if (sid == 0) rowptr[0] = 0;
    if (sid < n && blockIdx.x > 0) rowptr[sid + 1] += bsum[blockIdx.x - 1];
}

__global__ __launch_bounds__(256) void fill_k(const int* __restrict__ src, const int* __restrict__ dst,
                                              const int* __restrict__ rowptr, int* __restrict__ cursor,
                                              int* __restrict__ csrc, int* __restrict__ cdst, int e) {
    int i = blockIdx.x * 256 + threadIdx.x;
    if (i < e) {
        int d = dst[i];
        int pos = rowptr[d] + atomicAdd(&cursor[d], 1);
        csrc[pos] = src[i];
        cdst[pos] = d;
    }
}

// ---------------- W -> packed hi/lo bf16 MFMA fragments ----------------
// Bp layout: [ks=4][slot=16][lane=64][j=8] shorts, slot = 2n (+1 for lo part).
// Fragment (ks,n), lane (lhi*16+l15), elem j  ==  W[k= ks*32+lhi*8+j][ncol= n*16+l15].
__global__ __launch_bounds__(256) void wconv_k(const float* __restrict__ W, unsigned short* __restrict__ Bp) {
    int idx = blockIdx.x * 256 + threadIdx.x;    // 0..16383 = (k, ncol)
    int k = idx >> 7, nc = idx & 127;
    float v = W[idx];
    unsigned short h = f2bf_rtne(v);
    float hf = __uint_as_float((unsigned)h << 16);
    unsigned short lo = f2bf_rtne(v - hf);
    int n = nc >> 4, l15 = nc & 15, ks = k >> 5, lhi = (k >> 3) & 3, j = k & 7;
    int lanei = lhi * 16 + l15;
    Bp[(((ks * 16 + 2 * n) * 64) + lanei) * 8 + j] = h;
    Bp[(((ks * 16 + 2 * n + 1) * 64) + lanei) * 8 + j] = lo;
}

// ---------------- split-bf16 MFMA GEMM: C[M,128] = A @ W, fused el/er ----------------
// A*W ~= Ah*Wh + Ah*Wl + Al*Wh. Per block: 128 rows, 4 waves, wave owns 32 rows
// (2 M-frags x 8 N-frags of mfma_f32_16x16x32_bf16). B staged per-ks in
// double-buffered LDS (16KB slices, fragment-linear -> conflict-free ds_read_b128);
// round-7 lesson: per-wave global B-loads with MFMA right behind = pure latency stall.
__global__ __launch_bounds__(256) void gemm_mfma_k(const float* __restrict__ A,
        const unsigned short* __restrict__ Bp,
        const float* __restrict__ alp, const float* __restrict__ arp,
        float* __restrict__ C, float* __restrict__ el, float* __restrict__ er, int M) {
    __shared__ short Bs[2][16][64][8];   // 2 x 16KB
    int tid = threadIdx.x;
    int wv = tid >> 6, lane = tid & 63;
    int l15 = lane & 15, lhi = lane >> 4;
    int mb = blockIdx.x * 128 + wv * 32;

    f32x4 acc[2][8];
    #pragma unroll
    for (int f = 0; f < 2; f++)
        #pragma unroll
        for (int n = 0; n < 8; n++) acc[f][n] = (f32x4){0.f, 0.f, 0.f, 0.f};

    float alv[8], arv[8];
    #pragma unroll
    for (int n = 0; n < 8; n++) { alv[n] = alp[n * 16 + l15]; arv[n] = arp[n * 16 + l15]; }

    const float* a0p = A + (size_t)min(mb + l15, M - 1) * 128 + lhi * 8;
    const float* a1p = A + (size_t)min(mb + 16 + l15, M - 1) * 128 + lhi * 8;

    // stage ks=0
    {
        const float4* g = (const float4*)Bp;
        float4* s = (float4*)&Bs[0][0][0][0];
        #pragma unroll
        for (int p = 0; p < 4; p++) s[tid + p * 256] = g[tid + p * 256];
    }

    #pragma unroll
    for (int ks = 0; ks < 4; ks++) {
        int buf = ks & 1;
        __syncthreads();
        if (ks < 3) {   // prefetch next slice into other buffer; overlaps MFMAs below
            const float4* g = (const float4*)Bp + (size_t)(ks + 1) * 1024;
            float4* s = (float4*)&Bs[buf ^ 1][0][0][0];
            #pragma unroll
            for (int p = 0; p < 4; p++) s[tid + p * 256] = g[tid + p * 256];
        }
        // A rows for this k-slice: load + hi/lo split
        float av[8];
        bf16x8 a0h, a0l, a1h, a1l;
        *(float4*)(av)     = *(const float4*)(a0p + ks * 32);
        *(float4*)(av + 4) = *(const float4*)(a0p + ks * 32 + 4);
        #pragma unroll
        for (int j = 0; j < 8; j++) {
            unsigned short h = f2bf_rtne(av[j]);
            a0h[j] = (short)h;
            a0l[j] = (short)f2bf_rtne(av[j] - __uint_as_float((unsigned)h << 16));
        }
        *(float4*)(av)     = *(const float4*)(a1p + ks * 32);
        *(float4*)(av + 4) = *(const float4*)(a1p + ks * 32 + 4);
        #pragma unroll
        for (int j = 0; j < 8; j++) {
            unsigned short h = f2bf_rtne(av[j]);
            a1h[j] = (short)h;
            a1l[j] = (short)f2bf_rtne(av[j] - __uint_as_float((unsigned)h << 16));
        }
        const bf16x8* bsv = (const bf16x8*)&Bs[buf][0][0][0];
        #pragma unroll
        for (int n = 0; n < 8; n++) {
            bf16x8 bhv = bsv[(2 * n) * 64 + lane];
            bf16x8 blv = bsv[(2 * n + 1) * 64 + lane];
            acc[0][n] = __builtin_amdgcn_mfma_f32_16x16x32_bf16(a0h, bhv, acc[0][n], 0, 0, 0);
            acc[1][n] = __builtin_amdgcn_mfma_f32_16x16x32_bf16(a1h, bhv, acc[1][n], 0, 0, 0);
            acc[0][n] = __builtin_amdgcn_mfma_f32_16x16x32_bf16(a0l, bhv, acc[0][n], 0, 0, 0);
            acc[1][n] = __builtin_amdgcn_mfma_f32_16x16x32_bf16(a1l, bhv, acc[1][n], 0, 0, 0);
            acc[0][n] = __builtin_amdgcn_mfma_f32_16x16x32_bf16(a0h, blv, acc[0][n], 0, 0, 0);
            acc[1][n] = __builtin_amdgcn_mfma_f32_16x16x32_bf16(a1h, blv, acc[1][n], 0, 0, 0);
        }
    }

    // epilogue: C store + fused per-head el/er (D layout: row=(lane>>4)*4+i, col=lane&15)
    #pragma unroll
    for (int f = 0; f < 2; f++) {
        #pragma unroll
        for (int i = 0; i < 4; i++) {
            int r = mb + f * 16 + lhi * 4 + i;
            bool ok = (r < M);
            if (ok) {
                #pragma unroll
                for (int n = 0; n < 8; n++)
                    C[(size_t)r * 128 + n * 16 + l15] = acc[f][n][i];
            }
            float ph[4], qh[4];
            #pragma unroll
            for (int h = 0; h < 4; h++) {
                ph[h] = acc[f][2 * h][i] * alv[2 * h] + acc[f][2 * h + 1][i] * alv[2 * h + 1];
                qh[h] = acc[f][2 * h][i] * arv[2 * h] + acc[f][2 * h + 1][i] * arv[2 * h + 1];
            }
            #pragma unroll
            for (int off = 1; off < 16; off <<= 1) {
                #pragma unroll
                for (int h = 0; h < 4; h++) {
                    ph[h] += __shfl_xor(ph[h], off);
                    qh[h] += __shfl_xor(qh[h], off);
                }
            }
            if (ok && l15 < 8) {
                if (l15 < 4) {
                    float v = (l15 == 0) ? ph[0] : (l15 == 1) ? ph[1] : (l15 == 2) ? ph[2] : ph[3];
                    el[(size_t)r * 4 + l15] = v;
                } else {
                    int h = l15 - 4;
                    float v = (h == 0) ? qh[0] : (h == 1) ? qh[1] : (h == 2) ? qh[2] : qh[3];
                    er[(size_t)r * 4 + h] = v;
                }
            }
        }
    }
}

// ---------------- per-edge attention weights (CSR order, coalesced) ----------------
__global__ __launch_bounds__(256) void edgew_k(const int* __restrict__ csrc, const int* __restrict__ cdst,
                                               const float* __restrict__ el, const float* __restrict__ er,
                                               float* __restrict__ wbuf, int e) {
    int p = blockIdx.x * 256 + threadIdx.x;
    if (p >= e) return;
    int s = csrc[p], d = cdst[p];
    float4 l4 = *(const float4*)(el + (size_t)s * 4);
    float4 r4 = *(const float4*)(er + (size_t)d * 4);
    float e0 = l4.x + r4.x, e1 = l4.y + r4.y, e2 = l4.z + r4.z, e3 = l4.w + r4.w;
    e0 = (e0 > 0.f) ? e0 : 0.2f * e0;
    e1 = (e1 > 0.f) ? e1 : 0.2f * e1;
    e2 = (e2 > 0.f) ? e2 : 0.2f * e2;
    e3 = (e3 > 0.f) ? e3 : 0.2f * e3;
    *(float4*)(wbuf + (size_t)p * 4) = make_float4(__expf(e0), __expf(e1), __expf(e2), __expf(e3));
}

// ---------------- per-node aggregate + bias + ELU ----------------
__global__ __launch_bounds__(256) void aggregate_k(const float* __restrict__ feat, const float* __restrict__ wbuf,
                                                   const int* __restrict__ rowptr, const int* __restrict__ csrc,
                                                   const float* __restrict__ bias, float* __restrict__ out, int n) {
    int wid = threadIdx.x >> 6;
    int lane = threadIdx.x & 63;
    int node = blockIdx.x * 4 + wid;
    if (node >= n) return;
    int h = lane >> 4;
    int p0 = rowptr[node], p1 = rowptr[node + 1];
    float2 b2 = *(const float2*)(bias + lane * 2);
    float lsum = 0.f, a0 = 0.f, a1 = 0.f;
    int p = p0;
    for (; p + 4 <= p1; p += 4) {
        int s0 = csrc[p], s1 = csrc[p + 1], s2 = csrc[p + 2], s3 = csrc[p + 3];
        float w0 = wbuf[(size_t)p * 4 + h];
        float w1 = wbuf[(size_t)(p + 1) * 4 + h];
        float w2 = wbuf[(size_t)(p + 2) * 4 + h];
        float w3 = wbuf[(size_t)(p + 3) * 4 + h];
        float2 f0 = *(const float2*)(feat + (size_t)s0 * 128 + lane * 2);
        float2 f1 = *(const float2*)(feat + (size_t)s1 * 128 + lane * 2);
        float2 f2 = *(const float2*)(feat + (size_t)s2 * 128 + lane * 2);
        float2 f3 = *(const float2*)(feat + (size_t)s3 * 128 + lane * 2);
        lsum += (w0 + w1) + (w2 + w3);
        a0 += w0 * f0.x + w1 * f1.x + w2 * f2.x + w3 * f3.x;
        a1 += w0 * f0.y + w1 * f1.y + w2 * f2.y + w3 * f3.y;
    }
    for (; p < p1; ++p) {
        int s = csrc[p];
        float w = wbuf[(size_t)p * 4 + h];
        float2 f = *(const float2*)(feat + (size_t)s * 128 + lane * 2);
        lsum += w;
        a0 += w * f.x;
        a1 += w * f.y;
    }
    float inv = 1.f / fmaxf(lsum, 1e-9f);
    float v0 = a0 * inv + b2.x;
    float v1 = a1 * inv + b2.y;
    v0 = (v0 > 0.f) ? v0 : expm1f(v0);
    v1 = (v1 > 0.f) ? v1 : expm1f(v1);
    *(float2*)(out + (size_t)node * 128 + lane * 2) = make_float2(v0, v1);
}

// ---------------- projection: hp[N,32] = h[N,128] @ Wp[128,32] + bp ----------------
__global__ __launch_bounds__(256) void proj_k(const float* __restrict__ h, const float* __restrict__ Wp,
                                              const float* __restrict__ bp, float* __restrict__ hp, int n) {
    __shared__ float Ws[128 * 32];
    __shared__ float Hs[32][132];
    int tid = threadIdx.x;
    for (int i = tid; i < 4096; i += 256) Ws[i] = Wp[i];
    int n0 = blockIdx.x * 32;
    for (int i = tid; i < 1024; i += 256) {
        int r = i >> 5, c4 = i & 31;
        int node = n0 + r;
        float4 v = (node < n) ? *(const float4*)(h + (size_t)node * 128 + c4 * 4)
                              : make_float4(0.f, 0.f, 0.f, 0.f);
        *(float4*)&Hs[r][c4 * 4] = v;
    }
    __syncthreads();
    int r = tid >> 3;
    int node = n0 + r;
    int j0 = (tid & 7) * 4;
    if (node < n) {
        float a0 = bp[j0], a1 = bp[j0 + 1], a2 = bp[j0 + 2], a3 = bp[j0 + 3];
        #pragma unroll
        for (int k = 0; k < 128; k++) {
            float av = Hs[r][k];
            float4 w = *(const float4*)&Ws[k * 32 + j0];
            a0 += av * w.x; a1 += av * w.y; a2 += av * w.z; a3 += av * w.w;
        }
        *(float4*)(hp + (size_t)node * 32 + j0) = make_float4(a0, a1, a2, a3);
    }
}

// ---------------- pair predictor MLP ----------------
__global__ __launch_bounds__(256) void predictor_k(const float* __restrict__ hp,
                                                   const int* __restrict__ ps, const int* __restrict__ pd,
                                                   const int* __restrict__ ns, const int* __restrict__ nd,
                                                   const float* __restrict__ Wq1, const float* __restrict__ bq1,
                                                   const float* __restrict__ Wq2, const float* __restrict__ bq2,
                                                   const float* __restrict__ Wq3, const float* __restrict__ bq3,
                                                   float* __restrict__ out, int P) {
    __shared__ float w1[1024], w2[1024], w3[32], b1[32], b2[32];
    int tid = threadIdx.x;
    for (int i = tid; i < 1024; i += 256) { w1[i] = Wq1[i]; w2[i] = Wq2[i]; }
    if (tid < 32) { w3[tid] = Wq3[tid]; b1[tid] = bq1[tid]; b2[tid] = bq2[tid]; }
    __syncthreads();
    int gid = blockIdx.x * 256 + tid;
    if (gid >= 2 * P) return;
    int i = (gid < P) ? gid : gid - P;
    int a = (gid < P) ? ps[i] : ns[i];
    int b = (gid < P) ? pd[i] : nd[i];
    float z[32];
    const float4* ha = (const float4*)(hp + (size_t)a * 32);
    const float4* hb = (const float4*)(hp + (size_t)b * 32);
    #pragma unroll
    for (int q = 0; q < 8; q++) {
        float4 x = ha[q], y = hb[q];
        z[q * 4 + 0] = x.x * y.x; z[q * 4 + 1] = x.y * y.y;
        z[q * 4 + 2] = x.z * y.z; z[q * 4 + 3] = x.w * y.w;
    }
    float z1[32];
    #pragma unroll
    for (int j = 0; j < 32; j++) {
        float s = b1[j];
        #pragma unroll
        for (int k = 0; k < 32; k++) s += z[k] * w1[k * 32 + j];
        z1[j] = fmaxf(s, 0.f);
    }
    #pragma unroll
    for (int j = 0; j < 32; j++) {
        float s = b2[j];
        #pragma unroll
        for (int k = 0; k < 32; k++) s += z1[k] * w2[k * 32 + j];
        z[j] = fmaxf(s, 0.f);
    }
    float s3 = bq3[0];
    #pragma unroll
    for (int j = 0; j < 32; j++) s3 += z[j] * w3[j];
    out[gid] = s3;
}

// ---------------- launch ----------------
extern "C" void kernel_launch(void* const* d_in, const int* in_sizes, int n_in,
                              void* d_out, int out_size, void* d_ws, size_t ws_size,
                              hipStream_t stream) {
    const float* x   = (const float*)d_in[0];
    const int* src   = (const int*)d_in[1];
    const int* dst   = (const int*)d_in[2];
    const int* psrc  = (const int*)d_in[3];
    const int* pdst  = (const int*)d_in[4];
    const int* nsrc  = (const int*)d_in[5];
    const int* ndst  = (const int*)d_in[6];
    const float* W[3]  = { (const float*)d_in[7],  (const float*)d_in[11], (const float*)d_in[15] };
    const float* al[3] = { (const float*)d_in[8],  (const float*)d_in[12], (const float*)d_in[16] };
    const float* ar[3] = { (const float*)d_in[9],  (const float*)d_in[13], (const float*)d_in[17] };
    const float* bb[3] = { (const float*)d_in[10], (const float*)d_in[14], (const float*)d_in[18] };
    const float* Wp  = (const float*)d_in[19];
    const float* bp  = (const float*)d_in[20];
    const float* Wq1 = (const float*)d_in[21];
    const float* bq1 = (const float*)d_in[22];
    const float* Wq2 = (const float*)d_in[23];
    const float* bq2 = (const float*)d_in[24];
    const float* Wq3 = (const float*)d_in[25];
    const float* bq3 = (const float*)d_in[26];
    float* out = (float*)d_out;

    const int N = in_sizes[0] / 128;
    const int E = in_sizes[1];
    const int P = in_sizes[3];

    size_t off = 0;
    auto alloc = [&](size_t bytes) {
        void* p = (char*)d_ws + off;
        off += (bytes + 255) & ~(size_t)255;
        return p;
    };
    float* bufF  = (float*)alloc((size_t)N * 128 * 4);
    float* bufH  = (float*)alloc((size_t)N * 128 * 4);
    float* elA   = (float*)alloc((size_t)N * 4 * 4);
    float* erA   = (float*)alloc((size_t)N * 4 * 4);
    float* hp    = (float*)alloc((size_t)N * 32 * 4);
    int* rowptr  = (int*)alloc((size_t)(N + 1) * 4);
    int* csrc    = (int*)alloc((size_t)E * 4);
    int* cdst    = (int*)alloc((size_t)E * 4);
    float* wbuf  = (float*)alloc((size_t)E * 4 * 4);
    int* deg     = (int*)alloc((size_t)N * 4);
    int* cursor  = (int*)alloc((size_t)N * 4);
    int* bsum    = (int*)alloc(1024 * 4);
    unsigned short* Bp = (unsigned short*)alloc(32768 * 2);
    (void)ws_size;

    const int NB_E = (E + 255) / 256;
    const int NB_N = (N + 255) / 256;

    hipMemsetAsync(deg, 0, (size_t)N * 4, stream);
    hipMemsetAsync(cursor, 0, (size_t)N * 4, stream);

    hist_k<<<NB_E, 256, 0, stream>>>(dst, deg, E);
    scan1_k<<<NB_N, 256, 0, stream>>>(deg, rowptr, bsum, N);
    scan2_k<<<1, 512, 0, stream>>>(bsum, NB_N);
    scan3_k<<<NB_N, 256, 0, stream>>>(rowptr, bsum, N);
    fill_k<<<NB_E, 256, 0, stream>>>(src, dst, rowptr, cursor, csrc, cdst, E);

    const int GEMM_B = (N + 127) / 128;
    const float* hin = x;
    for (int l = 0; l < 3; l++) {
        wconv_k<<<64, 256, 0, stream>>>(W[l], Bp);
        gemm_mfma_k<<<GEMM_B, 256, 0, stream>>>(hin, Bp, al[l], ar[l], bufF, elA, erA, N);
        edgew_k<<<NB_E, 256, 0, stream>>>(csrc, cdst, elA, erA, wbuf, E);
        aggregate_k<<<(N + 3) / 4, 256, 0, stream>>>(bufF, wbuf, rowptr, csrc, bb[l], bufH, N);
        hin = bufH;
    }
    proj_k<<<(N + 31) / 32, 256, 0, stream>>>(bufH, Wp, bp, hp, N);
    predictor_k<<<(2 * P + 255) / 256, 256, 0, stream>>>(hp, psrc, pdst, nsrc, ndst,
                                                         Wq1, bq1, Wq2, bq2, Wq3, bq3, out, P);
}

// Round 9
// 487.991 us; speedup vs baseline: 2.1806x; 1.0403x over previous
//
#include <hip/hip_runtime.h>
#include <math.h>

typedef __attribute__((ext_vector_type(8))) short bf16x8;
typedef __attribute__((ext_vector_type(4))) float f32x4;

__device__ __forceinline__ unsigned short f2bf_rtne(float v) {
    unsigned u = __float_as_uint(v);
    u += 0x7FFFu + ((u >> 16) & 1u);
    return (unsigned short)(u >> 16);
}

// ---------------- CSR build ----------------
__global__ __launch_bounds__(256) void hist_k(const int* __restrict__ dst, int* __restrict__ deg, int e) {
    int i = blockIdx.x * 256 + threadIdx.x;
    if (i < e) atomicAdd(&deg[dst[i]], 1);
}

__global__ __launch_bounds__(256) void scan1_k(const int* __restrict__ deg, int* __restrict__ rowptr,
                                               int* __restrict__ bsum, int n) {
    __shared__ int sh[256];
    int tid = threadIdx.x;
    int sid = blockIdx.x * 256 + tid;
    int v = (sid < n) ? deg[sid] : 0;
    sh[tid] = v; __syncthreads();
    for (int off = 1; off < 256; off <<= 1) {
        int t = (tid >= off) ? sh[tid - off] : 0;
        __syncthreads();
        sh[tid] += t;
        __syncthreads();
    }
    if (sid < n) rowptr[sid + 1] = sh[tid];
    if (tid == 255) bsum[blockIdx.x] = sh[255];
}

__global__ __launch_bounds__(512) void scan2_k(int* __restrict__ bsum, int nb) {
    __shared__ int sh[512];
    int tid = threadIdx.x;
    sh[tid] = (tid < nb) ? bsum[tid] : 0;
    __syncthreads();
    for (int off = 1; off < 512; off <<= 1) {
        int t = (tid >= off) ? sh[tid - off] : 0;
        __syncthreads();
        sh[tid] += t;
        __syncthreads();
    }
    if (tid < nb) bsum[tid] = sh[tid];
}

__global__ __launch_bounds__(256) void scan3_k(int* __restrict__ rowptr, const int* __restrict__ bsum, int n) {
    int sid = blockIdx.x * 256 + threadIdx.x;
    if (sid == 0) rowptr[0] = 0;
    if (sid < n && blockIdx.x > 0) rowptr[sid + 1] += bsum[blockIdx.x - 1];
}

__global__ __launch_bounds__(256) void fill_k(const int* __restrict__ src, const int* __restrict__ dst,
                                              const int* __restrict__ rowptr, int* __restrict__ cursor,
                                              int* __restrict__ csrc, int* __restrict__ cdst, int e) {
    int i = blockIdx.x * 256 + threadIdx.x;
    if (i < e) {
        int d = dst[i];
        int pos = rowptr[d] + atomicAdd(&cursor[d], 1);
        csrc[pos] = src[i];
        cdst[pos] = d;
    }
}

// ---------------- W -> packed hi/lo bf16 MFMA fragments ----------------
// Bp layout: [ks=4][slot=16][lane=64][j=8] shorts, slot = 2n (hi) / 2n+1 (lo).
// Fragment (ks,n), lane (lhi*16+l15), elem j  ==  W[k= ks*32+lhi*8+j][ncol= n*16+l15].
__global__ __launch_bounds__(256) void wconv_k(const float* __restrict__ W, unsigned short* __restrict__ Bp) {
    int idx = blockIdx.x * 256 + threadIdx.x;    // 0..16383 = (k, ncol)
    int k = idx >> 7, nc = idx & 127;
    float v = W[idx];
    unsigned short h = f2bf_rtne(v);
    float hf = __uint_as_float((unsigned)h << 16);
    unsigned short lo = f2bf_rtne(v - hf);
    int n = nc >> 4, l15 = nc & 15, ks = k >> 5, lhi = (k >> 3) & 3, j = k & 7;
    int lanei = lhi * 16 + l15;
    Bp[(((ks * 16 + 2 * n) * 64) + lanei) * 8 + j] = h;
    Bp[(((ks * 16 + 2 * n + 1) * 64) + lanei) * 8 + j] = lo;
}

// ---------------- split-bf16 MFMA GEMM: C[M,128] = A @ W, fused el/er ----------------
// A*W ~= Ah*Wh + Ah*Wl + Al*Wh. Per block: 128 rows, 4 waves, wave owns 32 rows
// (2 M-frags x 8 N-frags of mfma_f32_16x16x32_bf16).
// Round-8 lesson: per-iteration global loads (A and B-prefetch consumed by ds_write)
// exposed full memory latency 4x/block at ~1.4 resident blocks/CU -> 88% stall.
// Now: ALL of B (hi+lo, full K = 64KB) staged once into single-buffer LDS; ALL of A
// hoisted into 16 in-flight float4 regs before the barrier. K-loop is reg+LDS only.
__global__ __launch_bounds__(256) void gemm_mfma_k(const float* __restrict__ A,
        const unsigned short* __restrict__ Bp,
        const float* __restrict__ alp, const float* __restrict__ arp,
        float* __restrict__ C, float* __restrict__ el, float* __restrict__ er, int M) {
    __shared__ short Bs[4][16][64][8];   // 64 KB -> 2 blocks/CU
    int tid = threadIdx.x;
    int wv = tid >> 6, lane = tid & 63;
    int l15 = lane & 15, lhi = lane >> 4;
    int mb = blockIdx.x * 128 + wv * 32;

    // stage all of B: 4096 float4s, 16 per thread, all issued together
    {
        const float4* g = (const float4*)Bp;
        float4* s = (float4*)&Bs[0][0][0][0];
        #pragma unroll
        for (int p = 0; p < 16; p++) s[tid + p * 256] = g[tid + p * 256];
    }

    // hoist all A loads (wave's 32 rows x full K): 16 independent float4s in flight
    const float* a0p = A + (size_t)min(mb + l15, M - 1) * 128 + lhi * 8;
    const float* a1p = A + (size_t)min(mb + 16 + l15, M - 1) * 128 + lhi * 8;
    float4 A0[4][2], A1[4][2];
    #pragma unroll
    for (int ks = 0; ks < 4; ks++) {
        A0[ks][0] = *(const float4*)(a0p + ks * 32);
        A0[ks][1] = *(const float4*)(a0p + ks * 32 + 4);
        A1[ks][0] = *(const float4*)(a1p + ks * 32);
        A1[ks][1] = *(const float4*)(a1p + ks * 32 + 4);
    }

    f32x4 acc[2][8];
    #pragma unroll
    for (int f = 0; f < 2; f++)
        #pragma unroll
        for (int n = 0; n < 8; n++) acc[f][n] = (f32x4){0.f, 0.f, 0.f, 0.f};

    float alv[8], arv[8];
    #pragma unroll
    for (int n = 0; n < 8; n++) { alv[n] = alp[n * 16 + l15]; arv[n] = arp[n * 16 + l15]; }

    __syncthreads();

    #pragma unroll
    for (int ks = 0; ks < 4; ks++) {
        // hi/lo split of this k-slice's A (registers only)
        float av[8];
        bf16x8 a0h, a0l, a1h, a1l;
        *(float4*)(av)     = A0[ks][0];
        *(float4*)(av + 4) = A0[ks][1];
        #pragma unroll
        for (int j = 0; j < 8; j++) {
            unsigned short h = f2bf_rtne(av[j]);
            a0h[j] = (short)h;
            a0l[j] = (short)f2bf_rtne(av[j] - __uint_as_float((unsigned)h << 16));
        }
        *(float4*)(av)     = A1[ks][0];
        *(float4*)(av + 4) = A1[ks][1];
        #pragma unroll
        for (int j = 0; j < 8; j++) {
            unsigned short h = f2bf_rtne(av[j]);
            a1h[j] = (short)h;
            a1l[j] = (short)f2bf_rtne(av[j] - __uint_as_float((unsigned)h << 16));
        }
        const bf16x8* bsv = (const bf16x8*)&Bs[ks][0][0][0];
        #pragma unroll
        for (int n = 0; n < 8; n++) {
            bf16x8 bhv = bsv[(2 * n) * 64 + lane];
            bf16x8 blv = bsv[(2 * n + 1) * 64 + lane];
            acc[0][n] = __builtin_amdgcn_mfma_f32_16x16x32_bf16(a0h, bhv, acc[0][n], 0, 0, 0);
            acc[1][n] = __builtin_amdgcn_mfma_f32_16x16x32_bf16(a1h, bhv, acc[1][n], 0, 0, 0);
            acc[0][n] = __builtin_amdgcn_mfma_f32_16x16x32_bf16(a0l, bhv, acc[0][n], 0, 0, 0);
            acc[1][n] = __builtin_amdgcn_mfma_f32_16x16x32_bf16(a1l, bhv, acc[1][n], 0, 0, 0);
            acc[0][n] = __builtin_amdgcn_mfma_f32_16x16x32_bf16(a0h, blv, acc[0][n], 0, 0, 0);
            acc[1][n] = __builtin_amdgcn_mfma_f32_16x16x32_bf16(a1h, blv, acc[1][n], 0, 0, 0);
        }
    }

    // epilogue: C store + fused per-head el/er (D layout: row=(lane>>4)*4+i, col=lane&15)
    #pragma unroll
    for (int f = 0; f < 2; f++) {
        #pragma unroll
        for (int i = 0; i < 4; i++) {
            int r = mb + f * 16 + lhi * 4 + i;
            bool ok = (r < M);
            if (ok) {
                #pragma unroll
                for (int n = 0; n < 8; n++)
                    C[(size_t)r * 128 + n * 16 + l15] = acc[f][n][i];
            }
            float ph[4], qh[4];
            #pragma unroll
            for (int h = 0; h < 4; h++) {
                ph[h] = acc[f][2 * h][i] * alv[2 * h] + acc[f][2 * h + 1][i] * alv[2 * h + 1];
                qh[h] = acc[f][2 * h][i] * arv[2 * h] + acc[f][2 * h + 1][i] * arv[2 * h + 1];
            }
            #pragma unroll
            for (int off = 1; off < 16; off <<= 1) {
                #pragma unroll
                for (int h = 0; h < 4; h++) {
                    ph[h] += __shfl_xor(ph[h], off);
                    qh[h] += __shfl_xor(qh[h], off);
                }
            }
            if (ok && l15 < 8) {
                if (l15 < 4) {
                    float v = (l15 == 0) ? ph[0] : (l15 == 1) ? ph[1] : (l15 == 2) ? ph[2] : ph[3];
                    el[(size_t)r * 4 + l15] = v;
                } else {
                    int h = l15 - 4;
                    float v = (h == 0) ? qh[0] : (h == 1) ? qh[1] : (h == 2) ? qh[2] : qh[3];
                    er[(size_t)r * 4 + h] = v;
                }
            }
        }
    }
}

// ---------------- per-edge attention weights (CSR order, coalesced) ----------------
__global__ __launch_bounds__(256) void edgew_k(const int* __restrict__ csrc, const int* __restrict__ cdst,
                                               const float* __restrict__ el, const float* __restrict__ er,
                                               float* __restrict__ wbuf, int e) {
    int p = blockIdx.x * 256 + threadIdx.x;
    if (p >= e) return;
    int s = csrc[p], d = cdst[p];
    float4 l4 = *(const float4*)(el + (size_t)s * 4);
    float4 r4 = *(const float4*)(er + (size_t)d * 4);
    float e0 = l4.x + r4.x, e1 = l4.y + r4.y, e2 = l4.z + r4.z, e3 = l4.w + r4.w;
    e0 = (e0 > 0.f) ? e0 : 0.2f * e0;
    e1 = (e1 > 0.f) ? e1 : 0.2f * e1;
    e2 = (e2 > 0.f) ? e2 : 0.2f * e2;
    e3 = (e3 > 0.f) ? e3 : 0.2f * e3;
    *(float4*)(wbuf + (size_t)p * 4) = make_float4(__expf(e0), __expf(e1), __expf(e2), __expf(e3));
}

// ---------------- per-node aggregate + bias + ELU ----------------
__global__ __launch_bounds__(256) void aggregate_k(const float* __restrict__ feat, const float* __restrict__ wbuf,
                                                   const int* __restrict__ rowptr, const int* __restrict__ csrc,
                                                   const float* __restrict__ bias, float* __restrict__ out, int n) {
    int wid = threadIdx.x >> 6;
    int lane = threadIdx.x & 63;
    int node = blockIdx.x * 4 + wid;
    if (node >= n) return;
    int h = lane >> 4;
    int p0 = rowptr[node], p1 = rowptr[node + 1];
    float2 b2 = *(const float2*)(bias + lane * 2);
    float lsum = 0.f, a0 = 0.f, a1 = 0.f;
    int p = p0;
    for (; p + 4 <= p1; p += 4) {
        int s0 = csrc[p], s1 = csrc[p + 1], s2 = csrc[p + 2], s3 = csrc[p + 3];
        float w0 = wbuf[(size_t)p * 4 + h];
        float w1 = wbuf[(size_t)(p + 1) * 4 + h];
        float w2 = wbuf[(size_t)(p + 2) * 4 + h];
        float w3 = wbuf[(size_t)(p + 3) * 4 + h];
        float2 f0 = *(const float2*)(feat + (size_t)s0 * 128 + lane * 2);
        float2 f1 = *(const float2*)(feat + (size_t)s1 * 128 + lane * 2);
        float2 f2 = *(const float2*)(feat + (size_t)s2 * 128 + lane * 2);
        float2 f3 = *(const float2*)(feat + (size_t)s3 * 128 + lane * 2);
        lsum += (w0 + w1) + (w2 + w3);
        a0 += w0 * f0.x + w1 * f1.x + w2 * f2.x + w3 * f3.x;
        a1 += w0 * f0.y + w1 * f1.y + w2 * f2.y + w3 * f3.y;
    }
    for (; p < p1; ++p) {
        int s = csrc[p];
        float w = wbuf[(size_t)p * 4 + h];
        float2 f = *(const float2*)(feat + (size_t)s * 128 + lane * 2);
        lsum += w;
        a0 += w * f.x;
        a1 += w * f.y;
    }
    float inv = 1.f / fmaxf(lsum, 1e-9f);
    float v0 = a0 * inv + b2.x;
    float v1 = a1 * inv + b2.y;
    v0 = (v0 > 0.f) ? v0 : expm1f(v0);
    v1 = (v1 > 0.f) ? v1 : expm1f(v1);
    *(float2*)(out + (size_t)node * 128 + lane * 2) = make_float2(v0, v1);
}

// ---------------- projection: hp[N,32] = h[N,128] @ Wp[128,32] + bp ----------------
__global__ __launch_bounds__(256) void proj_k(const float* __restrict__ h, const float* __restrict__ Wp,
                                              const float* __restrict__ bp, float* __restrict__ hp, int n) {
    __shared__ float Ws[128 * 32];
    __shared__ float Hs[32][132];
    int tid = threadIdx.x;
    for (int i = tid; i < 4096; i += 256) Ws[i] = Wp[i];
    int n0 = blockIdx.x * 32;
    for (int i = tid; i < 1024; i += 256) {
        int r = i >> 5, c4 = i & 31;
        int node = n0 + r;
        float4 v = (node < n) ? *(const float4*)(h + (size_t)node * 128 + c4 * 4)
                              : make_float4(0.f, 0.f, 0.f, 0.f);
        *(float4*)&Hs[r][c4 * 4] = v;
    }
    __syncthreads();
    int r = tid >> 3;
    int node = n0 + r;
    int j0 = (tid & 7) * 4;
    if (node < n) {
        float a0 = bp[j0], a1 = bp[j0 + 1], a2 = bp[j0 + 2], a3 = bp[j0 + 3];
        #pragma unroll
        for (int k = 0; k < 128; k++) {
            float av = Hs[r][k];
            float4 w = *(const float4*)&Ws[k * 32 + j0];
            a0 += av * w.x; a1 += av * w.y; a2 += av * w.z; a3 += av * w.w;
        }
        *(float4*)(hp + (size_t)node * 32 + j0) = make_float4(a0, a1, a2, a3);
    }
}

// ---------------- pair predictor MLP ----------------
__global__ __launch_bounds__(256) void predictor_k(const float* __restrict__ hp,
                                                   const int* __restrict__ ps, const int* __restrict__ pd,
                                                   const int* __restrict__ ns, const int* __restrict__ nd,
                                                   const float* __restrict__ Wq1, const float* __restrict__ bq1,
                                                   const float* __restrict__ Wq2, const float* __restrict__ bq2,
                                                   const float* __restrict__ Wq3, const float* __restrict__ bq3,
                                                   float* __restrict__ out, int P) {
    __shared__ float w1[1024], w2[1024], w3[32], b1[32], b2[32];
    int tid = threadIdx.x;
    for (int i = tid; i < 1024; i += 256) { w1[i] = Wq1[i]; w2[i] = Wq2[i]; }
    if (tid < 32) { w3[tid] = Wq3[tid]; b1[tid] = bq1[tid]; b2[tid] = bq2[tid]; }
    __syncthreads();
    int gid = blockIdx.x * 256 + tid;
    if (gid >= 2 * P) return;
    int i = (gid < P) ? gid : gid - P;
    int a = (gid < P) ? ps[i] : ns[i];
    int b = (gid < P) ? pd[i] : nd[i];
    float z[32];
    const float4* ha = (const float4*)(hp + (size_t)a * 32);
    const float4* hb = (const float4*)(hp + (size_t)b * 32);
    #pragma unroll
    for (int q = 0; q < 8; q++) {
        float4 x = ha[q], y = hb[q];
        z[q * 4 + 0] = x.x * y.x; z[q * 4 + 1] = x.y * y.y;
        z[q * 4 + 2] = x.z * y.z; z[q * 4 + 3] = x.w * y.w;
    }
    float z1[32];
    #pragma unroll
    for (int j = 0; j < 32; j++) {
        float s = b1[j];
        #pragma unroll
        for (int k = 0; k < 32; k++) s += z[k] * w1[k * 32 + j];
        z1[j] = fmaxf(s, 0.f);
    }
    #pragma unroll
    for (int j = 0; j < 32; j++) {
        float s = b2[j];
        #pragma unroll
        for (int k = 0; k < 32; k++) s += z1[k] * w2[k * 32 + j];
        z[j] = fmaxf(s, 0.f);
    }
    float s3 = bq3[0];
    #pragma unroll
    for (int j = 0; j < 32; j++) s3 += z[j] * w3[j];
    out[gid] = s3;
}

// ---------------- launch ----------------
extern "C" void kernel_launch(void* const* d_in, const int* in_sizes, int n_in,
                              void* d_out, int out_size, void* d_ws, size_t ws_size,
                              hipStream_t stream) {
    const float* x   = (const float*)d_in[0];
    const int* src   = (const int*)d_in[1];
    const int* dst   = (const int*)d_in[2];
    const int* psrc  = (const int*)d_in[3];
    const int* pdst  = (const int*)d_in[4];
    const int* nsrc  = (const int*)d_in[5];
    const int* ndst  = (const int*)d_in[6];
    const float* W[3]  = { (const float*)d_in[7],  (const float*)d_in[11], (const float*)d_in[15] };
    const float* al[3] = { (const float*)d_in[8],  (const float*)d_in[12], (const float*)d_in[16] };
    const float* ar[3] = { (const float*)d_in[9],  (const float*)d_in[13], (const float*)d_in[17] };
    const float* bb[3] = { (const float*)d_in[10], (const float*)d_in[14], (const float*)d_in[18] };
    const float* Wp  = (const float*)d_in[19];
    const float* bp  = (const float*)d_in[20];
    const float* Wq1 = (const float*)d_in[21];
    const float* bq1 = (const float*)d_in[22];
    const float* Wq2 = (const float*)d_in[23];
    const float* bq2 = (const float*)d_in[24];
    const float* Wq3 = (const float*)d_in[25];
    const float* bq3 = (const float*)d_in[26];
    float* out = (float*)d_out;

    const int N = in_sizes[0] / 128;
    const int E = in_sizes[1];
    const int P = in_sizes[3];

    size_t off = 0;
    auto alloc = [&](size_t bytes) {
        void* p = (char*)d_ws + off;
        off += (bytes + 255) & ~(size_t)255;
        return p;
    };
    float* bufF  = (float*)alloc((size_t)N * 128 * 4);
    float* bufH  = (float*)alloc((size_t)N * 128 * 4);
    float* elA   = (float*)alloc((size_t)N * 4 * 4);
    float* erA   = (float*)alloc((size_t)N * 4 * 4);
    float* hp    = (float*)alloc((size_t)N * 32 * 4);
    int* rowptr  = (int*)alloc((size_t)(N + 1) * 4);
    int* csrc    = (int*)alloc((size_t)E * 4);
    int* cdst    = (int*)alloc((size_t)E * 4);
    float* wbuf  = (float*)alloc((size_t)E * 4 * 4);
    int* deg     = (int*)alloc((size_t)N * 4);
    int* cursor  = (int*)alloc((size_t)N * 4);
    int* bsum    = (int*)alloc(1024 * 4);
    unsigned short* Bp = (unsigned short*)alloc(32768 * 2);
    (void)ws_size;

    const int NB_E = (E + 255) / 256;
    const int NB_N = (N + 255) / 256;

    hipMemsetAsync(deg, 0, (size_t)N * 4, stream);
    hipMemsetAsync(cursor, 0, (size_t)N * 4, stream);

    hist_k<<<NB_E, 256, 0, stream>>>(dst, deg, E);
    scan1_k<<<NB_N, 256, 0, stream>>>(deg, rowptr, bsum, N);
    scan2_k<<<1, 512, 0, stream>>>(bsum, NB_N);
    scan3_k<<<NB_N, 256, 0, stream>>>(rowptr, bsum, N);
    fill_k<<<NB_E, 256, 0, stream>>>(src, dst, rowptr, cursor, csrc, cdst, E);

    const int GEMM_B = (N + 127) / 128;
    const float* hin = x;
    for (int l = 0; l < 3; l++) {
        wconv_k<<<64, 256, 0, stream>>>(W[l], Bp);
        gemm_mfma_k<<<GEMM_B, 256, 0, stream>>>(hin, Bp, al[l], ar[l], bufF, elA, erA, N);
        edgew_k<<<NB_E, 256, 0, stream>>>(csrc, cdst, elA, erA, wbuf, E);
        aggregate_k<<<(N + 3) / 4, 256, 0, stream>>>(bufF, wbuf, rowptr, csrc, bb[l], bufH, N);
        hin = bufH;
    }
    proj_k<<<(N + 31) / 32, 256, 0, stream>>>(bufH, Wp, bp, hp, N);
    predictor_k<<<(2 * P + 255) / 256, 256, 0, stream>>>(hp, psrc, pdst, nsrc, ndst,
                                                         Wq1, bq1, Wq2, bq2, Wq3, bq3, out, P);
}

// Round 10
// 471.564 us; speedup vs baseline: 2.2566x; 1.0348x over previous
//
#include <hip/hip_runtime.h>
#include <math.h>

typedef __attribute__((ext_vector_type(8))) short bf16x8;
typedef __attribute__((ext_vector_type(4))) float f32x4;

__device__ __forceinline__ unsigned short f2bf_rtne(float v) {
    unsigned u = __float_as_uint(v);
    u += 0x7FFFu + ((u >> 16) & 1u);
    return (unsigned short)(u >> 16);
}

// ---------------- CSR build ----------------
__global__ __launch_bounds__(256) void hist_k(const int* __restrict__ dst, int* __restrict__ deg, int e) {
    int i = blockIdx.x * 256 + threadIdx.x;
    if (i < e) atomicAdd(&deg[dst[i]], 1);
}

__global__ __launch_bounds__(256) void scan1_k(const int* __restrict__ deg, int* __restrict__ rowptr,
                                               int* __restrict__ bsum, int n) {
    __shared__ int sh[256];
    int tid = threadIdx.x;
    int sid = blockIdx.x * 256 + tid;
    int v = (sid < n) ? deg[sid] : 0;
    sh[tid] = v; __syncthreads();
    for (int off = 1; off < 256; off <<= 1) {
        int t = (tid >= off) ? sh[tid - off] : 0;
        __syncthreads();
        sh[tid] += t;
        __syncthreads();
    }
    if (sid < n) rowptr[sid + 1] = sh[tid];
    if (tid == 255) bsum[blockIdx.x] = sh[255];
}

__global__ __launch_bounds__(512) void scan2_k(int* __restrict__ bsum, int nb) {
    __shared__ int sh[512];
    int tid = threadIdx.x;
    sh[tid] = (tid < nb) ? bsum[tid] : 0;
    __syncthreads();
    for (int off = 1; off < 512; off <<= 1) {
        int t = (tid >= off) ? sh[tid - off] : 0;
        __syncthreads();
        sh[tid] += t;
        __syncthreads();
    }
    if (tid < nb) bsum[tid] = sh[tid];
}

// finalizes rowptr AND initializes cursor = rowptr (fill uses cursor directly)
__global__ __launch_bounds__(256) void scan3_k(int* __restrict__ rowptr, int* __restrict__ cursor,
                                               const int* __restrict__ bsum, int n) {
    int sid = blockIdx.x * 256 + threadIdx.x;
    if (sid == 0) { rowptr[0] = 0; cursor[0] = 0; }
    if (sid < n) {
        int v = rowptr[sid + 1];
        if (blockIdx.x > 0) v += bsum[blockIdx.x - 1];
        rowptr[sid + 1] = v;
        cursor[sid + 1] = v;
    }
}

// round-9 lesson: two scattered 4B stores/edge -> 85MB write amplification.
// Now: one atomic (cursor pre-initialized to rowptr) + one scattered store.
__global__ __launch_bounds__(256) void fill_k(const int* __restrict__ src, const int* __restrict__ dst,
                                              int* __restrict__ cursor, int* __restrict__ csrc, int e) {
    int i = blockIdx.x * 256 + threadIdx.x;
    if (i < e) {
        int pos = atomicAdd(&cursor[dst[i]], 1);
        csrc[pos] = src[i];
    }
}

// ---------------- split-bf16 MFMA GEMM: C[M,128] = A @ W, fused el/er ----------------
// A*W ~= Ah*Wh + Ah*Wl + Al*Wh. Per block: 128 rows, 4 waves, wave owns 32 rows
// (2 M-frags x 8 N-frags of mfma_f32_16x16x32_bf16). W is split hi/lo IN-KERNEL
// (L2-hot 64KB read per block) straight into packed LDS fragments -> no wconv
// kernel, no Bp round-trip. All A hoisted to 16 in-flight float4s before barrier;
// K-loop is reg+LDS only (round-8 lesson).
__global__ __launch_bounds__(256) void gemm_mfma_k(const float* __restrict__ A,
        const float* __restrict__ Wg,
        const float* __restrict__ alp, const float* __restrict__ arp,
        float* __restrict__ C, float* __restrict__ el, float* __restrict__ er, int M) {
    __shared__ short Bs[4][16][64][8];   // 64 KB -> 2 blocks/CU
    int tid = threadIdx.x;
    int wv = tid >> 6, lane = tid & 63;
    int l15 = lane & 15, lhi = lane >> 4;
    int mb = blockIdx.x * 128 + wv * 32;

    // hoist all A loads (wave's 32 rows x full K): 16 independent float4s in flight
    const float* a0p = A + (size_t)min(mb + l15, M - 1) * 128 + lhi * 8;
    const float* a1p = A + (size_t)min(mb + 16 + l15, M - 1) * 128 + lhi * 8;
    float4 A0[4][2], A1[4][2];
    #pragma unroll
    for (int ks = 0; ks < 4; ks++) {
        A0[ks][0] = *(const float4*)(a0p + ks * 32);
        A0[ks][1] = *(const float4*)(a0p + ks * 32 + 4);
        A1[ks][0] = *(const float4*)(a1p + ks * 32);
        A1[ks][1] = *(const float4*)(a1p + ks * 32 + 4);
    }

    // in-kernel W hi/lo split into packed LDS fragments.
    // Octet o: grp=o>>7 (k-octet 8*grp..8*grp+7), nc=o&127 (output col).
    // lane-consecutive o -> consecutive nc -> coalesced 256B reads (L2-hot).
    #pragma unroll
    for (int i = 0; i < 8; i++) {
        int o = tid + i * 256;
        int grp = o >> 7, nc = o & 127;
        float wv8[8];
        #pragma unroll
        for (int j = 0; j < 8; j++) wv8[j] = Wg[(8 * grp + j) * 128 + nc];
        bf16x8 hi, lo;
        #pragma unroll
        for (int j = 0; j < 8; j++) {
            unsigned short h = f2bf_rtne(wv8[j]);
            hi[j] = (short)h;
            lo[j] = (short)f2bf_rtne(wv8[j] - __uint_as_float((unsigned)h << 16));
        }
        int ks = grp >> 2, lh2 = grp & 3, n = nc >> 4, l = nc & 15;
        *(bf16x8*)&Bs[ks][2 * n][lh2 * 16 + l][0] = hi;
        *(bf16x8*)&Bs[ks][2 * n + 1][lh2 * 16 + l][0] = lo;
    }

    f32x4 acc[2][8];
    #pragma unroll
    for (int f = 0; f < 2; f++)
        #pragma unroll
        for (int n = 0; n < 8; n++) acc[f][n] = (f32x4){0.f, 0.f, 0.f, 0.f};

    float alv[8], arv[8];
    #pragma unroll
    for (int n = 0; n < 8; n++) { alv[n] = alp[n * 16 + l15]; arv[n] = arp[n * 16 + l15]; }

    __syncthreads();

    #pragma unroll
    for (int ks = 0; ks < 4; ks++) {
        float av[8];
        bf16x8 a0h, a0l, a1h, a1l;
        *(float4*)(av)     = A0[ks][0];
        *(float4*)(av + 4) = A0[ks][1];
        #pragma unroll
        for (int j = 0; j < 8; j++) {
            unsigned short h = f2bf_rtne(av[j]);
            a0h[j] = (short)h;
            a0l[j] = (short)f2bf_rtne(av[j] - __uint_as_float((unsigned)h << 16));
        }
        *(float4*)(av)     = A1[ks][0];
        *(float4*)(av + 4) = A1[ks][1];
        #pragma unroll
        for (int j = 0; j < 8; j++) {
            unsigned short h = f2bf_rtne(av[j]);
            a1h[j] = (short)h;
            a1l[j] = (short)f2bf_rtne(av[j] - __uint_as_float((unsigned)h << 16));
        }
        const bf16x8* bsv = (const bf16x8*)&Bs[ks][0][0][0];
        #pragma unroll
        for (int n = 0; n < 8; n++) {
            bf16x8 bhv = bsv[(2 * n) * 64 + lane];
            bf16x8 blv = bsv[(2 * n + 1) * 64 + lane];
            acc[0][n] = __builtin_amdgcn_mfma_f32_16x16x32_bf16(a0h, bhv, acc[0][n], 0, 0, 0);
            acc[1][n] = __builtin_amdgcn_mfma_f32_16x16x32_bf16(a1h, bhv, acc[1][n], 0, 0, 0);
            acc[0][n] = __builtin_amdgcn_mfma_f32_16x16x32_bf16(a0l, bhv, acc[0][n], 0, 0, 0);
            acc[1][n] = __builtin_amdgcn_mfma_f32_16x16x32_bf16(a1l, bhv, acc[1][n], 0, 0, 0);
            acc[0][n] = __builtin_amdgcn_mfma_f32_16x16x32_bf16(a0h, blv, acc[0][n], 0, 0, 0);
            acc[1][n] = __builtin_amdgcn_mfma_f32_16x16x32_bf16(a1h, blv, acc[1][n], 0, 0, 0);
        }
    }

    // epilogue: C store + fused per-head el/er (D layout: row=(lane>>4)*4+i, col=lane&15)
    #pragma unroll
    for (int f = 0; f < 2; f++) {
        #pragma unroll
        for (int i = 0; i < 4; i++) {
            int r = mb + f * 16 + lhi * 4 + i;
            bool ok = (r < M);
            if (ok) {
                #pragma unroll
                for (int n = 0; n < 8; n++)
                    C[(size_t)r * 128 + n * 16 + l15] = acc[f][n][i];
            }
            float ph[4], qh[4];
            #pragma unroll
            for (int h = 0; h < 4; h++) {
                ph[h] = acc[f][2 * h][i] * alv[2 * h] + acc[f][2 * h + 1][i] * alv[2 * h + 1];
                qh[h] = acc[f][2 * h][i] * arv[2 * h] + acc[f][2 * h + 1][i] * arv[2 * h + 1];
            }
            #pragma unroll
            for (int off = 1; off < 16; off <<= 1) {
                #pragma unroll
                for (int h = 0; h < 4; h++) {
                    ph[h] += __shfl_xor(ph[h], off);
                    qh[h] += __shfl_xor(qh[h], off);
                }
            }
            if (ok && l15 < 8) {
                if (l15 < 4) {
                    float v = (l15 == 0) ? ph[0] : (l15 == 1) ? ph[1] : (l15 == 2) ? ph[2] : ph[3];
                    el[(size_t)r * 4 + l15] = v;
                } else {
                    int h = l15 - 4;
                    float v = (h == 0) ? qh[0] : (h == 1) ? qh[1] : (h == 2) ? qh[2] : qh[3];
                    er[(size_t)r * 4 + h] = v;
                }
            }
        }
    }
}

// ---------------- per-node aggregate (inline edge weights) + bias + ELU ----------------
// One wave per node; lane l handles features 2l,2l+1 (head h=l>>4).
// w = exp(lrelu(el[s]+er[node])) computed inline: er is loop-invariant, el[s*4+h]
// gather replaces the old wbuf gather 1-for-1 -> edgew kernel + wbuf buffer deleted.
__global__ __launch_bounds__(256) void aggregate_k(const float* __restrict__ feat, const float* __restrict__ el,
                                                   const float* __restrict__ er, const int* __restrict__ rowptr,
                                                   const int* __restrict__ csrc, const float* __restrict__ bias,
                                                   float* __restrict__ out, int n) {
    int wid = threadIdx.x >> 6;
    int lane = threadIdx.x & 63;
    int node = blockIdx.x * 4 + wid;
    if (node >= n) return;
    int h = lane >> 4;
    int p0 = rowptr[node], p1 = rowptr[node + 1];
    float erv = er[(size_t)node * 4 + h];
    float2 b2 = *(const float2*)(bias + lane * 2);
    float lsum = 0.f, a0 = 0.f, a1 = 0.f;
    int p = p0;
    for (; p + 4 <= p1; p += 4) {
        int s0 = csrc[p], s1 = csrc[p + 1], s2 = csrc[p + 2], s3 = csrc[p + 3];
        float e0 = el[(size_t)s0 * 4 + h] + erv;
        float e1 = el[(size_t)s1 * 4 + h] + erv;
        float e2 = el[(size_t)s2 * 4 + h] + erv;
        float e3 = el[(size_t)s3 * 4 + h] + erv;
        e0 = (e0 > 0.f) ? e0 : 0.2f * e0;
        e1 = (e1 > 0.f) ? e1 : 0.2f * e1;
        e2 = (e2 > 0.f) ? e2 : 0.2f * e2;
        e3 = (e3 > 0.f) ? e3 : 0.2f * e3;
        float2 f0 = *(const float2*)(feat + (size_t)s0 * 128 + lane * 2);
        float2 f1 = *(const float2*)(feat + (size_t)s1 * 128 + lane * 2);
        float2 f2 = *(const float2*)(feat + (size_t)s2 * 128 + lane * 2);
        float2 f3 = *(const float2*)(feat + (size_t)s3 * 128 + lane * 2);
        float w0 = __expf(e0), w1 = __expf(e1), w2 = __expf(e2), w3 = __expf(e3);
        lsum += (w0 + w1) + (w2 + w3);
        a0 += w0 * f0.x + w1 * f1.x + w2 * f2.x + w3 * f3.x;
        a1 += w0 * f0.y + w1 * f1.y + w2 * f2.y + w3 * f3.y;
    }
    for (; p < p1; ++p) {
        int s = csrc[p];
        float e = el[(size_t)s * 4 + h] + erv;
        e = (e > 0.f) ? e : 0.2f * e;
        float w = __expf(e);
        float2 f = *(const float2*)(feat + (size_t)s * 128 + lane * 2);
        lsum += w;
        a0 += w * f.x;
        a1 += w * f.y;
    }
    float inv = 1.f / fmaxf(lsum, 1e-9f);
    float v0 = a0 * inv + b2.x;
    float v1 = a1 * inv + b2.y;
    v0 = (v0 > 0.f) ? v0 : expm1f(v0);
    v1 = (v1 > 0.f) ? v1 : expm1f(v1);
    *(float2*)(out + (size_t)node * 128 + lane * 2) = make_float2(v0, v1);
}

// ---------------- projection: hp[N,32] = h[N,128] @ Wp[128,32] + bp ----------------
__global__ __launch_bounds__(256) void proj_k(const float* __restrict__ h, const float* __restrict__ Wp,
                                              const float* __restrict__ bp, float* __restrict__ hp, int n) {
    __shared__ float Ws[128 * 32];
    __shared__ float Hs[32][132];
    int tid = threadIdx.x;
    for (int i = tid; i < 4096; i += 256) Ws[i] = Wp[i];
    int n0 = blockIdx.x * 32;
    for (int i = tid; i < 1024; i += 256) {
        int r = i >> 5, c4 = i & 31;
        int node = n0 + r;
        float4 v = (node < n) ? *(const float4*)(h + (size_t)node * 128 + c4 * 4)
                              : make_float4(0.f, 0.f, 0.f, 0.f);
        *(float4*)&Hs[r][c4 * 4] = v;
    }
    __syncthreads();
    int r = tid >> 3;
    int node = n0 + r;
    int j0 = (tid & 7) * 4;
    if (node < n) {
        float a0 = bp[j0], a1 = bp[j0 + 1], a2 = bp[j0 + 2], a3 = bp[j0 + 3];
        #pragma unroll
        for (int k = 0; k < 128; k++) {
            float av = Hs[r][k];
            float4 w = *(const float4*)&Ws[k * 32 + j0];
            a0 += av * w.x; a1 += av * w.y; a2 += av * w.z; a3 += av * w.w;
        }
        *(float4*)(hp + (size_t)node * 32 + j0) = make_float4(a0, a1, a2, a3);
    }
}

// ---------------- pair predictor MLP ----------------
__global__ __launch_bounds__(256) void predictor_k(const float* __restrict__ hp,
                                                   const int* __restrict__ ps, const int* __restrict__ pd,
                                                   const int* __restrict__ ns, const int* __restrict__ nd,
                                                   const float* __restrict__ Wq1, const float* __restrict__ bq1,
                                                   const float* __restrict__ Wq2, const float* __restrict__ bq2,
                                                   const float* __restrict__ Wq3, const float* __restrict__ bq3,
                                                   float* __restrict__ out, int P) {
    __shared__ float w1[1024], w2[1024], w3[32], b1[32], b2[32];
    int tid = threadIdx.x;
    for (int i = tid; i < 1024; i += 256) { w1[i] = Wq1[i]; w2[i] = Wq2[i]; }
    if (tid < 32) { w3[tid] = Wq3[tid]; b1[tid] = bq1[tid]; b2[tid] = bq2[tid]; }
    __syncthreads();
    int gid = blockIdx.x * 256 + tid;
    if (gid >= 2 * P) return;
    int i = (gid < P) ? gid : gid - P;
    int a = (gid < P) ? ps[i] : ns[i];
    int b = (gid < P) ? pd[i] : nd[i];
    float z[32];
    const float4* ha = (const float4*)(hp + (size_t)a * 32);
    const float4* hb = (const float4*)(hp + (size_t)b * 32);
    #pragma unroll
    for (int q = 0; q < 8; q++) {
        float4 x = ha[q], y = hb[q];
        z[q * 4 + 0] = x.x * y.x; z[q * 4 + 1] = x.y * y.y;
        z[q * 4 + 2] = x.z * y.z; z[q * 4 + 3] = x.w * y.w;
    }
    float z1[32];
    #pragma unroll
    for (int j = 0; j < 32; j++) {
        float s = b1[j];
        #pragma unroll
        for (int k = 0; k < 32; k++) s += z[k] * w1[k * 32 + j];
        z1[j] = fmaxf(s, 0.f);
    }
    #pragma unroll
    for (int j = 0; j < 32; j++) {
        float s = b2[j];
        #pragma unroll
        for (int k = 0; k < 32; k++) s += z1[k] * w2[k * 32 + j];
        z[j] = fmaxf(s, 0.f);
    }
    float s3 = bq3[0];
    #pragma unroll
    for (int j = 0; j < 32; j++) s3 += z[j] * w3[j];
    out[gid] = s3;
}

// ---------------- launch ----------------
extern "C" void kernel_launch(void* const* d_in, const int* in_sizes, int n_in,
                              void* d_out, int out_size, void* d_ws, size_t ws_size,
                              hipStream_t stream) {
    const float* x   = (const float*)d_in[0];
    const int* src   = (const int*)d_in[1];
    const int* dst   = (const int*)d_in[2];
    const int* psrc  = (const int*)d_in[3];
    const int* pdst  = (const int*)d_in[4];
    const int* nsrc  = (const int*)d_in[5];
    const int* ndst  = (const int*)d_in[6];
    const float* W[3]  = { (const float*)d_in[7],  (const float*)d_in[11], (const float*)d_in[15] };
    const float* al[3] = { (const float*)d_in[8],  (const float*)d_in[12], (const float*)d_in[16] };
    const float* ar[3] = { (const float*)d_in[9],  (const float*)d_in[13], (const float*)d_in[17] };
    const float* bb[3] = { (const float*)d_in[10], (const float*)d_in[14], (const float*)d_in[18] };
    const float* Wp  = (const float*)d_in[19];
    const float* bp  = (const float*)d_in[20];
    const float* Wq1 = (const float*)d_in[21];
    const float* bq1 = (const float*)d_in[22];
    const float* Wq2 = (const float*)d_in[23];
    const float* bq2 = (const float*)d_in[24];
    const float* Wq3 = (const float*)d_in[25];
    const float* bq3 = (const float*)d_in[26];
    float* out = (float*)d_out;

    const int N = in_sizes[0] / 128;
    const int E = in_sizes[1];
    const int P = in_sizes[3];

    size_t off = 0;
    auto alloc = [&](size_t bytes) {
        void* p = (char*)d_ws + off;
        off += (bytes + 255) & ~(size_t)255;
        return p;
    };
    float* bufF  = (float*)alloc((size_t)N * 128 * 4);
    float* bufH  = (float*)alloc((size_t)N * 128 * 4);
    float* elA   = (float*)alloc((size_t)N * 4 * 4);
    float* erA   = (float*)alloc((size_t)N * 4 * 4);
    float* hp    = (float*)alloc((size_t)N * 32 * 4);
    int* rowptr  = (int*)alloc((size_t)(N + 1) * 4);
    int* cursor  = (int*)alloc((size_t)(N + 1) * 4);
    int* csrc    = (int*)alloc((size_t)E * 4);
    int* deg     = (int*)alloc((size_t)N * 4);
    int* bsum    = (int*)alloc(1024 * 4);
    (void)ws_size;

    const int NB_E = (E + 255) / 256;
    const int NB_N = (N + 255) / 256;

    hipMemsetAsync(deg, 0, (size_t)N * 4, stream);

    hist_k<<<NB_E, 256, 0, stream>>>(dst, deg, E);
    scan1_k<<<NB_N, 256, 0, stream>>>(deg, rowptr, bsum, N);
    scan2_k<<<1, 512, 0, stream>>>(bsum, NB_N);
    scan3_k<<<NB_N, 256, 0, stream>>>(rowptr, cursor, bsum, N);
    fill_k<<<NB_E, 256, 0, stream>>>(src, dst, cursor, csrc, E);

    const int GEMM_B = (N + 127) / 128;
    const float* hin = x;
    for (int l = 0; l < 3; l++) {
        gemm_mfma_k<<<GEMM_B, 256, 0, stream>>>(hin, W[l], al[l], ar[l], bufF, elA, erA, N);
        aggregate_k<<<(N + 3) / 4, 256, 0, stream>>>(bufF, elA, erA, rowptr, csrc, bb[l], bufH, N);
        hin = bufH;
    }
    proj_k<<<(N + 31) / 32, 256, 0, stream>>>(bufH, Wp, bp, hp, N);
    predictor_k<<<(2 * P + 255) / 256, 256, 0, stream>>>(hp, psrc, pdst, nsrc, ndst,
                                                         Wq1, bq1, Wq2, bq2, Wq3, bq3, out, P);
}

// Round 11
// 469.656 us; speedup vs baseline: 2.2658x; 1.0041x over previous
//
#include <hip/hip_runtime.h>
#include <math.h>

typedef __attribute__((ext_vector_type(8))) short bf16x8;
typedef __attribute__((ext_vector_type(4))) float f32x4;

__device__ __forceinline__ unsigned short f2bf_rtne(float v) {
    unsigned u = __float_as_uint(v);
    u += 0x7FFFu + ((u >> 16) & 1u);
    return (unsigned short)(u >> 16);
}

// ---------------- CSR build ----------------
__global__ __launch_bounds__(256) void hist_k(const int* __restrict__ dst, int* __restrict__ deg, int e) {
    int i = blockIdx.x * 256 + threadIdx.x;
    if (i < e) atomicAdd(&deg[dst[i]], 1);
}

__global__ __launch_bounds__(256) void scan1_k(const int* __restrict__ deg, int* __restrict__ rowptr,
                                               int* __restrict__ bsum, int n) {
    __shared__ int sh[256];
    int tid = threadIdx.x;
    int sid = blockIdx.x * 256 + tid;
    int v = (sid < n) ? deg[sid] : 0;
    sh[tid] = v; __syncthreads();
    for (int off = 1; off < 256; off <<= 1) {
        int t = (tid >= off) ? sh[tid - off] : 0;
        __syncthreads();
        sh[tid] += t;
        __syncthreads();
    }
    if (sid < n) rowptr[sid + 1] = sh[tid];
    if (tid == 255) bsum[blockIdx.x] = sh[255];
}

__global__ __launch_bounds__(512) void scan2_k(int* __restrict__ bsum, int nb) {
    __shared__ int sh[512];
    int tid = threadIdx.x;
    sh[tid] = (tid < nb) ? bsum[tid] : 0;
    __syncthreads();
    for (int off = 1; off < 512; off <<= 1) {
        int t = (tid >= off) ? sh[tid - off] : 0;
        __syncthreads();
        sh[tid] += t;
        __syncthreads();
    }
    if (tid < nb) bsum[tid] = sh[tid];
}

// finalizes rowptr AND initializes cursor = rowptr (fill uses cursor directly)
__global__ __launch_bounds__(256) void scan3_k(int* __restrict__ rowptr, int* __restrict__ cursor,
                                               const int* __restrict__ bsum, int n) {
    int sid = blockIdx.x * 256 + threadIdx.x;
    if (sid == 0) { rowptr[0] = 0; cursor[0] = 0; }
    if (sid < n) {
        int v = rowptr[sid + 1];
        if (blockIdx.x > 0) v += bsum[blockIdx.x - 1];
        rowptr[sid + 1] = v;
        cursor[sid + 1] = v;
    }
}

__global__ __launch_bounds__(256) void fill_k(const int* __restrict__ src, const int* __restrict__ dst,
                                              int* __restrict__ cursor, int* __restrict__ csrc, int e) {
    int i = blockIdx.x * 256 + threadIdx.x;
    if (i < e) {
        int pos = atomicAdd(&cursor[dst[i]], 1);
        csrc[pos] = src[i];
    }
}

// ---------------- W -> packed hi/lo bf16 MFMA fragments ----------------
// Bp layout: [ks=4][slot=16][lane=64][j=8] shorts, slot = 2n (hi) / 2n+1 (lo).
// Fragment (ks,n), lane (lhi*16+l15), elem j  ==  W[k= ks*32+lhi*8+j][ncol= n*16+l15].
// Round-11: precomputed again (round-9 folded it per-block: 64 scalar loads + ~128
// f2bf per thread x 782 blocks of VALU before any MFMA at 8 waves/CU -> pure serial cost).
__global__ __launch_bounds__(256) void wconv_k(const float* __restrict__ W, unsigned short* __restrict__ Bp) {
    int idx = blockIdx.x * 256 + threadIdx.x;    // 0..16383 = (k, ncol)
    int k = idx >> 7, nc = idx & 127;
    float v = W[idx];
    unsigned short h = f2bf_rtne(v);
    float hf = __uint_as_float((unsigned)h << 16);
    unsigned short lo = f2bf_rtne(v - hf);
    int n = nc >> 4, l15 = nc & 15, ks = k >> 5, lhi = (k >> 3) & 3, j = k & 7;
    int lanei = lhi * 16 + l15;
    Bp[(((ks * 16 + 2 * n) * 64) + lanei) * 8 + j] = h;
    Bp[(((ks * 16 + 2 * n + 1) * 64) + lanei) * 8 + j] = lo;
}

// ---------------- split-bf16 MFMA GEMM: C[M,128] = A @ W, fused el/er ----------------
// A*W ~= Ah*Wh + Ah*Wl + Al*Wh. Per block: 128 rows, 4 waves, wave owns 32 rows
// (2 M-frags x 8 N-frags of mfma_f32_16x16x32_bf16). Staging = linear float4 copy of
// packed Bp (no conversion math), overlapped with 16 hoisted in-flight A-loads;
// K-loop is reg+LDS only (round-8 lesson).
__global__ __launch_bounds__(256) void gemm_mfma_k(const float* __restrict__ A,
        const unsigned short* __restrict__ Bp,
        const float* __restrict__ alp, const float* __restrict__ arp,
        float* __restrict__ C, float* __restrict__ el, float* __restrict__ er, int M) {
    __shared__ short Bs[4][16][64][8];   // 64 KB -> 2 blocks/CU
    int tid = threadIdx.x;
    int wv = tid >> 6, lane = tid & 63;
    int l15 = lane & 15, lhi = lane >> 4;
    int mb = blockIdx.x * 128 + wv * 32;

    // hoist all A loads (wave's 32 rows x full K): 16 independent float4s in flight
    const float* a0p = A + (size_t)min(mb + l15, M - 1) * 128 + lhi * 8;
    const float* a1p = A + (size_t)min(mb + 16 + l15, M - 1) * 128 + lhi * 8;
    float4 A0[4][2], A1[4][2];
    #pragma unroll
    for (int ks = 0; ks < 4; ks++) {
        A0[ks][0] = *(const float4*)(a0p + ks * 32);
        A0[ks][1] = *(const float4*)(a0p + ks * 32 + 4);
        A1[ks][0] = *(const float4*)(a1p + ks * 32);
        A1[ks][1] = *(const float4*)(a1p + ks * 32 + 4);
    }

    // stage packed B (hi+lo, full K = 64KB): pure linear copy, 16 float4/thread
    {
        const float4* g = (const float4*)Bp;
        float4* s = (float4*)&Bs[0][0][0][0];
        #pragma unroll
        for (int p = 0; p < 16; p++) s[tid + p * 256] = g[tid + p * 256];
    }

    f32x4 acc[2][8];
    #pragma unroll
    for (int f = 0; f < 2; f++)
        #pragma unroll
        for (int n = 0; n < 8; n++) acc[f][n] = (f32x4){0.f, 0.f, 0.f, 0.f};

    float alv[8], arv[8];
    #pragma unroll
    for (int n = 0; n < 8; n++) { alv[n] = alp[n * 16 + l15]; arv[n] = arp[n * 16 + l15]; }

    __syncthreads();

    #pragma unroll
    for (int ks = 0; ks < 4; ks++) {
        float av[8];
        bf16x8 a0h, a0l, a1h, a1l;
        *(float4*)(av)     = A0[ks][0];
        *(float4*)(av + 4) = A0[ks][1];
        #pragma unroll
        for (int j = 0; j < 8; j++) {
            unsigned short h = f2bf_rtne(av[j]);
            a0h[j] = (short)h;
            a0l[j] = (short)f2bf_rtne(av[j] - __uint_as_float((unsigned)h << 16));
        }
        *(float4*)(av)     = A1[ks][0];
        *(float4*)(av + 4) = A1[ks][1];
        #pragma unroll
        for (int j = 0; j < 8; j++) {
            unsigned short h = f2bf_rtne(av[j]);
            a1h[j] = (short)h;
            a1l[j] = (short)f2bf_rtne(av[j] - __uint_as_float((unsigned)h << 16));
        }
        const bf16x8* bsv = (const bf16x8*)&Bs[ks][0][0][0];
        #pragma unroll
        for (int n = 0; n < 8; n++) {
            bf16x8 bhv = bsv[(2 * n) * 64 + lane];
            bf16x8 blv = bsv[(2 * n + 1) * 64 + lane];
            acc[0][n] = __builtin_amdgcn_mfma_f32_16x16x32_bf16(a0h, bhv, acc[0][n], 0, 0, 0);
            acc[1][n] = __builtin_amdgcn_mfma_f32_16x16x32_bf16(a1h, bhv, acc[1][n], 0, 0, 0);
            acc[0][n] = __builtin_amdgcn_mfma_f32_16x16x32_bf16(a0l, bhv, acc[0][n], 0, 0, 0);
            acc[1][n] = __builtin_amdgcn_mfma_f32_16x16x32_bf16(a1l, bhv, acc[1][n], 0, 0, 0);
            acc[0][n] = __builtin_amdgcn_mfma_f32_16x16x32_bf16(a0h, blv, acc[0][n], 0, 0, 0);
            acc[1][n] = __builtin_amdgcn_mfma_f32_16x16x32_bf16(a1h, blv, acc[1][n], 0, 0, 0);
        }
    }

    // epilogue: C store + fused per-head el/er (D layout: row=(lane>>4)*4+i, col=lane&15)
    #pragma unroll
    for (int f = 0; f < 2; f++) {
        #pragma unroll
        for (int i = 0; i < 4; i++) {
            int r = mb + f * 16 + lhi * 4 + i;
            bool ok = (r < M);
            if (ok) {
                #pragma unroll
                for (int n = 0; n < 8; n++)
                    C[(size_t)r * 128 + n * 16 + l15] = acc[f][n][i];
            }
            float ph[4], qh[4];
            #pragma unroll
            for (int h = 0; h < 4; h++) {
                ph[h] = acc[f][2 * h][i] * alv[2 * h] + acc[f][2 * h + 1][i] * alv[2 * h + 1];
                qh[h] = acc[f][2 * h][i] * arv[2 * h] + acc[f][2 * h + 1][i] * arv[2 * h + 1];
            }
            #pragma unroll
            for (int off = 1; off < 16; off <<= 1) {
                #pragma unroll
                for (int h = 0; h < 4; h++) {
                    ph[h] += __shfl_xor(ph[h], off);
                    qh[h] += __shfl_xor(qh[h], off);
                }
            }
            if (ok && l15 < 8) {
                if (l15 < 4) {
                    float v = (l15 == 0) ? ph[0] : (l15 == 1) ? ph[1] : (l15 == 2) ? ph[2] : ph[3];
                    el[(size_t)r * 4 + l15] = v;
                } else {
                    int h = l15 - 4;
                    float v = (h == 0) ? qh[0] : (h == 1) ? qh[1] : (h == 2) ? qh[2] : qh[3];
                    er[(size_t)r * 4 + h] = v;
                }
            }
        }
    }
}

// ---------------- per-node aggregate (inline edge weights) + bias + ELU ----------------
// One wave per node; lane l handles features 2l,2l+1 (head h=l>>4). Unroll-8 keeps
// 8 row-gathers in flight (latency regime: VALUBusy~47%, HBM~48% at unroll-4).
__global__ __launch_bounds__(256) void aggregate_k(const float* __restrict__ feat, const float* __restrict__ el,
                                                   const float* __restrict__ er, const int* __restrict__ rowptr,
                                                   const int* __restrict__ csrc, const float* __restrict__ bias,
                                                   float* __restrict__ out, int n) {
    int wid = threadIdx.x >> 6;
    int lane = threadIdx.x & 63;
    int node = blockIdx.x * 4 + wid;
    if (node >= n) return;
    int h = lane >> 4;
    int p0 = rowptr[node], p1 = rowptr[node + 1];
    float erv = er[(size_t)node * 4 + h];
    float2 b2 = *(const float2*)(bias + lane * 2);
    float lsum = 0.f, a0 = 0.f, a1 = 0.f;
    int p = p0;
    for (; p + 8 <= p1; p += 8) {
        int s[8];
        float e[8];
        float2 f[8];
        #pragma unroll
        for (int q = 0; q < 8; q++) s[q] = csrc[p + q];
        #pragma unroll
        for (int q = 0; q < 8; q++) e[q] = el[(size_t)s[q] * 4 + h] + erv;
        #pragma unroll
        for (int q = 0; q < 8; q++) f[q] = *(const float2*)(feat + (size_t)s[q] * 128 + lane * 2);
        #pragma unroll
        for (int q = 0; q < 8; q++) {
            float eq = (e[q] > 0.f) ? e[q] : 0.2f * e[q];
            float w = __expf(eq);
            lsum += w;
            a0 += w * f[q].x;
            a1 += w * f[q].y;
        }
    }
    for (; p + 4 <= p1; p += 4) {
        int s0 = csrc[p], s1 = csrc[p + 1], s2 = csrc[p + 2], s3 = csrc[p + 3];
        float e0 = el[(size_t)s0 * 4 + h] + erv;
        float e1 = el[(size_t)s1 * 4 + h] + erv;
        float e2 = el[(size_t)s2 * 4 + h] + erv;
        float e3 = el[(size_t)s3 * 4 + h] + erv;
        e0 = (e0 > 0.f) ? e0 : 0.2f * e0;
        e1 = (e1 > 0.f) ? e1 : 0.2f * e1;
        e2 = (e2 > 0.f) ? e2 : 0.2f * e2;
        e3 = (e3 > 0.f) ? e3 : 0.2f * e3;
        float2 f0 = *(const float2*)(feat + (size_t)s0 * 128 + lane * 2);
        float2 f1 = *(const float2*)(feat + (size_t)s1 * 128 + lane * 2);
        float2 f2 = *(const float2*)(feat + (size_t)s2 * 128 + lane * 2);
        float2 f3 = *(const float2*)(feat + (size_t)s3 * 128 + lane * 2);
        float w0 = __expf(e0), w1 = __expf(e1), w2 = __expf(e2), w3 = __expf(e3);
        lsum += (w0 + w1) + (w2 + w3);
        a0 += w0 * f0.x + w1 * f1.x + w2 * f2.x + w3 * f3.x;
        a1 += w0 * f0.y + w1 * f1.y + w2 * f2.y + w3 * f3.y;
    }
    for (; p < p1; ++p) {
        int s = csrc[p];
        float e = el[(size_t)s * 4 + h] + erv;
        e = (e > 0.f) ? e : 0.2f * e;
        float w = __expf(e);
        float2 f = *(const float2*)(feat + (size_t)s * 128 + lane * 2);
        lsum += w;
        a0 += w * f.x;
        a1 += w * f.y;
    }
    float inv = 1.f / fmaxf(lsum, 1e-9f);
    float v0 = a0 * inv + b2.x;
    float v1 = a1 * inv + b2.y;
    v0 = (v0 > 0.f) ? v0 : expm1f(v0);
    v1 = (v1 > 0.f) ? v1 : expm1f(v1);
    *(float2*)(out + (size_t)node * 128 + lane * 2) = make_float2(v0, v1);
}

// ---------------- projection: hp[N,32] = h[N,128] @ Wp[128,32] + bp ----------------
__global__ __launch_bounds__(256) void proj_k(const float* __restrict__ h, const float* __restrict__ Wp,
                                              const float* __restrict__ bp, float* __restrict__ hp, int n) {
    __shared__ float Ws[128 * 32];
    __shared__ float Hs[32][132];
    int tid = threadIdx.x;
    for (int i = tid; i < 4096; i += 256) Ws[i] = Wp[i];
    int n0 = blockIdx.x * 32;
    for (int i = tid; i < 1024; i += 256) {
        int r = i >> 5, c4 = i & 31;
        int node = n0 + r;
        float4 v = (node < n) ? *(const float4*)(h + (size_t)node * 128 + c4 * 4)
                              : make_float4(0.f, 0.f, 0.f, 0.f);
        *(float4*)&Hs[r][c4 * 4] = v;
    }
    __syncthreads();
    int r = tid >> 3;
    int node = n0 + r;
    int j0 = (tid & 7) * 4;
    if (node < n) {
        float a0 = bp[j0], a1 = bp[j0 + 1], a2 = bp[j0 + 2], a3 = bp[j0 + 3];
        #pragma unroll
        for (int k = 0; k < 128; k++) {
            float av = Hs[r][k];
            float4 w = *(const float4*)&Ws[k * 32 + j0];
            a0 += av * w.x; a1 += av * w.y; a2 += av * w.z; a3 += av * w.w;
        }
        *(float4*)(hp + (size_t)node * 32 + j0) = make_float4(a0, a1, a2, a3);
    }
}

// ---------------- pair predictor MLP ----------------
__global__ __launch_bounds__(256) void predictor_k(const float* __restrict__ hp,
                                                   const int* __restrict__ ps, const int* __restrict__ pd,
                                                   const int* __restrict__ ns, const int* __restrict__ nd,
                                                   const float* __restrict__ Wq1, const float* __restrict__ bq1,
                                                   const float* __restrict__ Wq2, const float* __restrict__ bq2,
                                                   const float* __restrict__ Wq3, const float* __restrict__ bq3,
                                                   float* __restrict__ out, int P) {
    __shared__ float w1[1024], w2[1024], w3[32], b1[32], b2[32];
    int tid = threadIdx.x;
    for (int i = tid; i < 1024; i += 256) { w1[i] = Wq1[i]; w2[i] = Wq2[i]; }
    if (tid < 32) { w3[tid] = Wq3[tid]; b1[tid] = bq1[tid]; b2[tid] = bq2[tid]; }
    __syncthreads();
    int gid = blockIdx.x * 256 + tid;
    if (gid >= 2 * P) return;
    int i = (gid < P) ? gid : gid - P;
    int a = (gid < P) ? ps[i] : ns[i];
    int b = (gid < P) ? pd[i] : nd[i];
    float z[32];
    const float4* ha = (const float4*)(hp + (size_t)a * 32);
    const float4* hb = (const float4*)(hp + (size_t)b * 32);
    #pragma unroll
    for (int q = 0; q < 8; q++) {
        float4 x = ha[q], y = hb[q];
        z[q * 4 + 0] = x.x * y.x; z[q * 4 + 1] = x.y * y.y;
        z[q * 4 + 2] = x.z * y.z; z[q * 4 + 3] = x.w * y.w;
    }
    float z1[32];
    #pragma unroll
    for (int j = 0; j < 32; j++) {
        float s = b1[j];
        #pragma unroll
        for (int k = 0; k < 32; k++) s += z[k] * w1[k * 32 + j];
        z1[j] = fmaxf(s, 0.f);
    }
    #pragma unroll
    for (int j = 0; j < 32; j++) {
        float s = b2[j];
        #pragma unroll
        for (int k = 0; k < 32; k++) s += z1[k] * w2[k * 32 + j];
        z[j] = fmaxf(s, 0.f);
    }
    float s3 = bq3[0];
    #pragma unroll
    for (int j = 0; j < 32; j++) s3 += z[j] * w3[j];
    out[gid] = s3;
}

// ---------------- launch ----------------
extern "C" void kernel_launch(void* const* d_in, const int* in_sizes, int n_in,
                              void* d_out, int out_size, void* d_ws, size_t ws_size,
                              hipStream_t stream) {
    const float* x   = (const float*)d_in[0];
    const int* src   = (const int*)d_in[1];
    const int* dst   = (const int*)d_in[2];
    const int* psrc  = (const int*)d_in[3];
    const int* pdst  = (const int*)d_in[4];
    const int* nsrc  = (const int*)d_in[5];
    const int* ndst  = (const int*)d_in[6];
    const float* W[3]  = { (const float*)d_in[7],  (const float*)d_in[11], (const float*)d_in[15] };
    const float* al[3] = { (const float*)d_in[8],  (const float*)d_in[12], (const float*)d_in[16] };
    const float* ar[3] = { (const float*)d_in[9],  (const float*)d_in[13], (const float*)d_in[17] };
    const float* bb[3] = { (const float*)d_in[10], (const float*)d_in[14], (const float*)d_in[18] };
    const float* Wp  = (const float*)d_in[19];
    const float* bp  = (const float*)d_in[20];
    const float* Wq1 = (const float*)d_in[21];
    const float* bq1 = (const float*)d_in[22];
    const float* Wq2 = (const float*)d_in[23];
    const float* bq2 = (const float*)d_in[24];
    const float* Wq3 = (const float*)d_in[25];
    const float* bq3 = (const float*)d_in[26];
    float* out = (float*)d_out;

    const int N = in_sizes[0] / 128;
    const int E = in_sizes[1];
    const int P = in_sizes[3];

    size_t off = 0;
    auto alloc = [&](size_t bytes) {
        void* p = (char*)d_ws + off;
        off += (bytes + 255) & ~(size_t)255;
        return p;
    };
    float* bufF  = (float*)alloc((size_t)N * 128 * 4);
    float* bufH  = (float*)alloc((size_t)N * 128 * 4);
    float* elA   = (float*)alloc((size_t)N * 4 * 4);
    float* erA   = (float*)alloc((size_t)N * 4 * 4);
    float* hp    = (float*)alloc((size_t)N * 32 * 4);
    int* rowptr  = (int*)alloc((size_t)(N + 1) * 4);
    int* cursor  = (int*)alloc((size_t)(N + 1) * 4);
    int* csrc    = (int*)alloc((size_t)E * 4);
    int* deg     = (int*)alloc((size_t)N * 4);
    int* bsum    = (int*)alloc(1024 * 4);
    unsigned short* Bp = (unsigned short*)alloc(32768 * 2);
    (void)ws_size;

    const int NB_E = (E + 255) / 256;
    const int NB_N = (N + 255) / 256;

    hipMemsetAsync(deg, 0, (size_t)N * 4, stream);

    hist_k<<<NB_E, 256, 0, stream>>>(dst, deg, E);
    scan1_k<<<NB_N, 256, 0, stream>>>(deg, rowptr, bsum, N);
    scan2_k<<<1, 512, 0, stream>>>(bsum, NB_N);
    scan3_k<<<NB_N, 256, 0, stream>>>(rowptr, cursor, bsum, N);
    fill_k<<<NB_E, 256, 0, stream>>>(src, dst, cursor, csrc, E);

    const int GEMM_B = (N + 127) / 128;
    const float* hin = x;
    for (int l = 0; l < 3; l++) {
        wconv_k<<<64, 256, 0, stream>>>(W[l], Bp);
        gemm_mfma_k<<<GEMM_B, 256, 0, stream>>>(hin, Bp, al[l], ar[l], bufF, elA, erA, N);
        aggregate_k<<<(N + 3) / 4, 256, 0, stream>>>(bufF, elA, erA, rowptr, csrc, bb[l], bufH, N);
        hin = bufH;
    }
    proj_k<<<(N + 31) / 32, 256, 0, stream>>>(bufH, Wp, bp, hp, N);
    predictor_k<<<(2 * P + 255) / 256, 256, 0, stream>>>(hp, psrc, pdst, nsrc, ndst,
                                                         Wq1, bq1, Wq2, bq2, Wq3, bq3, out, P);
}